// Round 15
// baseline (973.029 us; speedup 1.0000x reference)
//
#include <hip/hip_runtime.h>
#include <cstdint>

#define NUM_CLASSES 20
#define KSEL 5
#define M_PTS 10000
#define C_DIM 256
#define HW 16384
#define NQB 64           // queries per block
#define NJB 128          // j rows per tile
#define NT 79            // ceil(10000/128); 79*128 = 10112
#define MPAD 10112
#define INFV 1e30f

// ws layout (bytes)
#define WS_MN_OFF 0                      // float mn[10112]          = 40448 B
#define WS_MW_OFF 40448u                 // ushort mw[10000*256]     = 5120000 B
#define WS_XB_OFF 5160448u               // ushort xb[32768*256]     = 16777216 B
#define WS_TOTAL  21937664u

typedef short short8 __attribute__((ext_vector_type(8)));
typedef float f32x4 __attribute__((ext_vector_type(4)));

#define MFMA16(a, b, c) __builtin_amdgcn_mfma_f32_16x16x32_bf16(a, b, c, 0, 0, 0)

__device__ __forceinline__ uint pk2(float a, float b) {   // RNE f32->bf16 pair
  uint ua = __float_as_uint(a), ub = __float_as_uint(b);
  ua = (ua + 0x7fffu + ((ua >> 16) & 1u)) >> 16;
  ub = (ub + 0x7fffu + ((ub >> 16) & 1u)) >> 16;
  return (ua & 0xffffu) | (ub << 16);
}

// pinned global loads: volatile asm cannot be sunk past the selection VALU
__device__ __forceinline__ short8 gld16(const ushort* p) {
  short8 r;
  asm volatile("global_load_dwordx4 %0, %1, off" : "=v"(r) : "v"(p) : "memory");
  return r;
}
__device__ __forceinline__ f32x4 gldf4(const float* p) {
  f32x4 r;
  asm volatile("global_load_dwordx4 %0, %1, off" : "=v"(r) : "v"(p) : "memory");
  return r;
}
#define VMWAIT() do { asm volatile("s_waitcnt vmcnt(0)" ::: "memory"); \
                      __builtin_amdgcn_sched_barrier(0); } while (0)
#define SBAR()   __builtin_amdgcn_sched_barrier(0)

// ---- prep 1: m -> bf16 rows + fp32 norms (INF for padded rows) ----
__global__ void conv_m(const float* __restrict__ mx, ushort* __restrict__ mw,
                       float* __restrict__ mn) {
  const int t = threadIdx.x;
  const int r = blockIdx.x * 64 + (t >> 2);
  const int sg = t & 3;
  if (r >= MPAD) return;
  if (r >= M_PTS) { if (sg == 0) mn[r] = INFV; return; }
  const float4* src = (const float4*)(mx + (size_t)r * C_DIM + sg * 64);
  float4 v[16];
#pragma unroll
  for (int k = 0; k < 16; ++k) v[k] = src[k];
  uint u[32];
  float np = 0.f;
#pragma unroll
  for (int k = 0; k < 16; ++k) {
    u[2 * k]     = pk2(v[k].x, v[k].y);
    u[2 * k + 1] = pk2(v[k].z, v[k].w);
    np = fmaf(v[k].x, v[k].x, np); np = fmaf(v[k].y, v[k].y, np);
    np = fmaf(v[k].z, v[k].z, np); np = fmaf(v[k].w, v[k].w, np);
  }
  uint4* dst = (uint4*)(mw + (size_t)r * C_DIM + sg * 64);
#pragma unroll
  for (int i = 0; i < 8; ++i) dst[i] = *(const uint4*)&u[4 * i];
  np += __shfl_xor(np, 1);
  np += __shfl_xor(np, 2);
  if (sg == 0) mn[r] = np;
}

// ---- prep 2: x[b][c][hw] -> xb[n][c] bf16 (n = b*16384 + hw) ----
__global__ void conv_x(const float* __restrict__ x, ushort* __restrict__ xb) {
  const int t = threadIdx.x;
  const int n = blockIdx.x * 64 + (t & 63);
  const int seg = t >> 6;                      // c range [seg*64, seg*64+64)
  const int bb = n >> 14, hw = n & (HW - 1);
  const float* src = x + (size_t)bb * C_DIM * HW + hw;
  uint u[32];
#pragma unroll 8
  for (int k = 0; k < 32; ++k) {
    const int c = seg * 64 + 2 * k;
    const float a0 = src[(size_t)c * HW];      // coalesced across lanes
    const float a1 = src[(size_t)(c + 1) * HW];
    u[k] = pk2(a0, a1);
  }
  uint4* dst = (uint4*)(xb + (size_t)n * C_DIM + seg * 64);
#pragma unroll
  for (int i = 0; i < 8; ++i) dst[i] = *(const uint4*)&u[4 * i];
}

// ---- main: 512 blocks x 512 thr, __launch_bounds__(512,2) -> 256-VGPR class,
// 1 block/CU (grid runs as 2 sequential full-occupancy rounds).
// NO LDS / NO BARRIERS in the main loop. Pinned software pipeline per tile:
//   s_waitcnt vmcnt(0) + sched_barrier   (tile t frags + mn landed)
//   32 MFMA (register-only)              (consumes frags -> reissue is WAR-safe)
//   sched_barrier
//   issue 16 asm global_load_dwordx4 (tile t+1 frags) + 2 asm mn loads
//   sched_barrier
//   selection VALU                        (hides the L2 latency of the issue)
// mn is double-buffered (selection of t reads it after t+1's issue).
__global__ __launch_bounds__(512, 2) void knn_big(
    const float* __restrict__ x, const float* __restrict__ mx,
    const ushort* __restrict__ mw, const float* __restrict__ mn,
    const ushort* __restrict__ xb, const int* __restrict__ my,
    float* __restrict__ out)
{
  __shared__ struct { float Lv[16][KSEL][NQB]; int Lj[16][KSEL][NQB]; } sm;  // 40 KB

  const int t  = threadIdx.x;
  const int w  = t >> 6;
  const int l  = t & 63;
  const int wj = w >> 1;        // row block: wj*32 .. +32
  const int wq = w & 1;         // col block: wq*32 .. +32
  const int lr = l & 15;
  const int lg = l >> 4;

  const int q0  = blockIdx.x * NQB;
  const int bb  = q0 >> 14;
  const int hw0 = q0 & (HW - 1);

  // ---- B fragments in registers: 2 qf x 8 ks (64 VGPR), loaded once ----
  short8 bq[2][8];
#pragma unroll
  for (int qf = 0; qf < 2; ++qf) {
    const ushort* xrow = xb + (size_t)(q0 + wq * 32 + qf * 16 + lr) * C_DIM;
#pragma unroll
    for (int ks = 0; ks < 8; ++ks)
      bq[qf][ks] = *(const short8*)(xrow + ks * 32 + lg * 8);
  }

  float lv[2][KSEL]; int lj[2][KSEL];
#pragma unroll
  for (int qf = 0; qf < 2; ++qf)
#pragma unroll
    for (int e = 0; e < KSEL; ++e) { lv[qf][e] = INFV; lj[qf][e] = 0x7fffffff; }

  const int br0 = wj * 32 + lr;           // A-frag rows (tile-local)
  const int br1 = br0 + 16;

  const ushort* aw0 = mw + (size_t)br0 * C_DIM + lg * 8;   // walk +64KB/tile
  const ushort* aw1 = mw + (size_t)br1 * C_DIM + lg * 8;
  const float*  mnp = mn + wj * 32 + 4 * lg;               // walk +128/tile

  short8 fr[2][8];              // current tile A-frags (64 VGPR, WAR-recycled)
  f32x4 mnA0, mnA1, mnB0, mnB1; // double-buffered norms

#define ISSUE_FRAGS() do {                                                    \
    _Pragma("unroll")                                                         \
    for (int ks = 0; ks < 8; ++ks) {                                          \
      fr[0][ks] = gld16(aw0 + ks * 32);                                       \
      fr[1][ks] = gld16(aw1 + ks * 32);                                       \
    }                                                                         \
    aw0 += NJB * C_DIM; aw1 += NJB * C_DIM;                                   \
  } while (0)

#define ISSUE_FRAGS_CLAMPED() do {                                            \
    const int j0_ = (NT - 1) * NJB;                                           \
    int r0_ = j0_ + br0; if (r0_ >= M_PTS) r0_ = M_PTS - 1;                   \
    int r1_ = j0_ + br1; if (r1_ >= M_PTS) r1_ = M_PTS - 1;                   \
    const ushort* t0_ = mw + (size_t)r0_ * C_DIM + lg * 8;                    \
    const ushort* t1_ = mw + (size_t)r1_ * C_DIM + lg * 8;                    \
    _Pragma("unroll")                                                         \
    for (int ks = 0; ks < 8; ++ks) {                                          \
      fr[0][ks] = gld16(t0_ + ks * 32);                                       \
      fr[1][ks] = gld16(t1_ + ks * 32);                                       \
    }                                                                         \
  } while (0)

#define ISSUE_MN(M0, M1) do {                                                 \
    M0 = gldf4(mnp); M1 = gldf4(mnp + 16); mnp += NJB;                        \
  } while (0)

#define MFMA_TILE() do {                                                      \
    _Pragma("unroll")                                                         \
    for (int ks = 0; ks < 8; ++ks) {                                          \
      _Pragma("unroll")                                                       \
      for (int qf = 0; qf < 2; ++qf) {                                        \
        acc[0][qf] = MFMA16(fr[0][ks], bq[qf][ks], acc[0][qf]);               \
        acc[1][qf] = MFMA16(fr[1][ks], bq[qf][ks], acc[1][qf]);               \
      }                                                                       \
    }                                                                         \
  } while (0)

#define SEL_TILE(J0S, MN0, MN1) do {                                          \
    _Pragma("unroll")                                                         \
    for (int jf = 0; jf < 2; ++jf) {                                          \
      const f32x4 mn4 = (jf == 0) ? MN0 : MN1;                                \
      const int jb = (J0S) + wj * 32 + jf * 16 + 4 * lg;                      \
      _Pragma("unroll")                                                       \
      for (int qf = 0; qf < 2; ++qf) {                                        \
        _Pragma("unroll")                                                     \
        for (int e = 0; e < 4; ++e) {                                         \
          const float sc = fmaf(-2.f, acc[jf][qf][e], mn4[e]);                \
          if (sc < lv[qf][4]) {  /* asc-j + strict '<' == top_k tie-break */  \
            const int jg = jb + e;                                            \
            const float v0 = lv[qf][0], v1 = lv[qf][1], v2 = lv[qf][2], v3 = lv[qf][3]; \
            const int   i0 = lj[qf][0], i1 = lj[qf][1], i2 = lj[qf][2], i3 = lj[qf][3]; \
            const bool c0 = sc < v0, c1 = sc < v1, c2 = sc < v2, c3 = sc < v3; \
            lv[qf][4] = c3 ? v3 : sc;             lj[qf][4] = c3 ? i3 : jg;   \
            lv[qf][3] = c3 ? (c2 ? v2 : sc) : v3; lj[qf][3] = c3 ? (c2 ? i2 : jg) : i3; \
            lv[qf][2] = c2 ? (c1 ? v1 : sc) : v2; lj[qf][2] = c2 ? (c1 ? i1 : jg) : i2; \
            lv[qf][1] = c1 ? (c0 ? v0 : sc) : v1; lj[qf][1] = c1 ? (c0 ? i0 : jg) : i1; \
            lv[qf][0] = c0 ? sc : v0;             lj[qf][0] = c0 ? jg : i0;   \
          }                                                                   \
        }                                                                     \
      }                                                                       \
    }                                                                         \
  } while (0)

#define TILE_BODY(JT, MN_CUR0, MN_CUR1, MN_NXT0, MN_NXT1, ISSUE_NEXT)         \
  do {                                                                        \
    f32x4 acc[2][2];                                                          \
    _Pragma("unroll")                                                         \
    for (int jf = 0; jf < 2; ++jf)                                            \
      _Pragma("unroll")                                                       \
      for (int qf = 0; qf < 2; ++qf) acc[jf][qf] = (f32x4){0.f, 0.f, 0.f, 0.f}; \
    VMWAIT();                         /* tile frags + mn landed */            \
    MFMA_TILE();                      /* consume frags */                     \
    SBAR();                                                                   \
    ISSUE_NEXT;                       /* pinned loads for next tile */        \
    ISSUE_MN(MN_NXT0, MN_NXT1);                                               \
    SBAR();                                                                   \
    SEL_TILE((JT) * NJB, MN_CUR0, MN_CUR1);  /* hides load latency */         \
  } while (0)

  // prologue: tile 0
  ISSUE_FRAGS();
  ISSUE_MN(mnA0, mnA1);

  for (int p = 0; p < 39; ++p) {            // pairs: tiles 2p, 2p+1 (0..77)
    TILE_BODY(2 * p, mnA0, mnA1, mnB0, mnB1, ISSUE_FRAGS());
    if (p < 38) {
      TILE_BODY(2 * p + 1, mnB0, mnB1, mnA0, mnA1, ISSUE_FRAGS());
    } else {
      TILE_BODY(2 * p + 1, mnB0, mnB1, mnA0, mnA1, ISSUE_FRAGS_CLAMPED());
    }
  }
  // tile 78 (clamped frags already in fr; mn in mnA; no further issue)
  {
    f32x4 acc[2][2];
#pragma unroll
    for (int jf = 0; jf < 2; ++jf)
#pragma unroll
      for (int qf = 0; qf < 2; ++qf) acc[jf][qf] = (f32x4){0.f, 0.f, 0.f, 0.f};
    VMWAIT();
    MFMA_TILE();
    SEL_TILE((NT - 1) * NJB, mnA0, mnA1);
  }
#undef TILE_BODY
#undef SEL_TILE
#undef MFMA_TILE
#undef ISSUE_MN
#undef ISSUE_FRAGS_CLAMPED
#undef ISSUE_FRAGS

  // ---- epilogue: 16 lists/query ([s][e][q], q innermost -> conflict-free),
  // merge -> top-8, fp64 re-rank, vote, one-hot write ----
  __syncthreads();
  {
    const int s = wj * 4 + lg;            // list slot (lg owns rows 4lg..4lg+3)
#pragma unroll
    for (int qf = 0; qf < 2; ++qf) {
      const int q = wq * 32 + qf * 16 + lr;
#pragma unroll
      for (int e = 0; e < KSEL; ++e) { sm.Lv[s][e][q] = lv[qf][e]; sm.Lj[s][e][q] = lj[qf][e]; }
    }
  }
  __syncthreads();

  if (t < NQB) {                          // thread t finalizes query q0 + t
    float bv[8]; int bj2[8];
#pragma unroll
    for (int k = 0; k < 8; ++k) { bv[k] = INFV; bj2[k] = 0x7fffffff; }
    for (int s = 0; s < 16; ++s) {
#pragma unroll
      for (int e = 0; e < KSEL; ++e) {
        const float v = sm.Lv[s][e][t];
        const int  j = sm.Lj[s][e][t];
        if (v < bv[7] || (v == bv[7] && j < bj2[7])) {
          int pos = 7;
          while (pos > 0 && (bv[pos - 1] > v || (bv[pos - 1] == v && bj2[pos - 1] > j))) {
            bv[pos] = bv[pos - 1]; bj2[pos] = bj2[pos - 1]; --pos;
          }
          bv[pos] = v; bj2[pos] = j;
        }
      }
    }
    const float *m0 = mx + (size_t)bj2[0] * C_DIM, *m1 = mx + (size_t)bj2[1] * C_DIM;
    const float *m2 = mx + (size_t)bj2[2] * C_DIM, *m3 = mx + (size_t)bj2[3] * C_DIM;
    const float *m4 = mx + (size_t)bj2[4] * C_DIM, *m5 = mx + (size_t)bj2[5] * C_DIM;
    const float *m6 = mx + (size_t)bj2[6] * C_DIM, *m7 = mx + (size_t)bj2[7] * C_DIM;
    const float* xq = x + (size_t)bb * C_DIM * HW + hw0 + t;
    double d0 = 0, d1 = 0, d2 = 0, d3 = 0, d4 = 0, d5 = 0, d6 = 0, d7 = 0;
#pragma unroll 4
    for (int c = 0; c < C_DIM; ++c) {
      const double xv = (double)xq[(size_t)c * HW];
      double dd;
      dd = xv - (double)m0[c]; d0 = fma(dd, dd, d0);
      dd = xv - (double)m1[c]; d1 = fma(dd, dd, d1);
      dd = xv - (double)m2[c]; d2 = fma(dd, dd, d2);
      dd = xv - (double)m3[c]; d3 = fma(dd, dd, d3);
      dd = xv - (double)m4[c]; d4 = fma(dd, dd, d4);
      dd = xv - (double)m5[c]; d5 = fma(dd, dd, d5);
      dd = xv - (double)m6[c]; d6 = fma(dd, dd, d6);
      dd = xv - (double)m7[c]; d7 = fma(dd, dd, d7);
    }
    const double dv[8] = {d0, d1, d2, d3, d4, d5, d6, d7};
    const int    jvv[8] = {bj2[0], bj2[1], bj2[2], bj2[3], bj2[4], bj2[5], bj2[6], bj2[7]};
    int labs[KSEL]; unsigned used = 0;
#pragma unroll
    for (int n = 0; n < KSEL; ++n) {
      double bd = 1e300; int bj = 0x7fffffff; int bk = 0;
#pragma unroll
      for (int k = 0; k < 8; ++k) {
        const bool avail = ((used >> k) & 1u) == 0u;
        if (avail && (dv[k] < bd || (dv[k] == bd && jvv[k] < bj))) {
          bd = dv[k]; bj = jvv[k]; bk = k;
        }
      }
      used |= (1u << bk);
      labs[n] = my[bj];
    }
    int bestLab = NUM_CLASSES, bestCnt = 0;
#pragma unroll
    for (int a = 0; a < KSEL; ++a) {
      int cnt = 0;
#pragma unroll
      for (int b2 = 0; b2 < KSEL; ++b2) cnt += (labs[b2] == labs[a]) ? 1 : 0;
      if (cnt > bestCnt || (cnt == bestCnt && labs[a] < bestLab)) {
        bestCnt = cnt; bestLab = labs[a];
      }
    }
    float* ob = out + (size_t)bb * NUM_CLASSES * HW + hw0 + t;
#pragma unroll
    for (int cls = 0; cls < NUM_CLASSES; ++cls)
      ob[(size_t)cls * HW] = (cls == bestLab) ? 1.0f : 0.0f;   // coalesced per plane
  }
}

// ================= fallback (round-6 kernel, proven): used if ws too small ========
#define FNQB 64
#define FNJB 128
#define FNT 79
#define FXP 264
#define FMP 40
__global__ __launch_bounds__(256, 2) void knn_fb(
    const float* __restrict__ x, const float* __restrict__ mx,
    const int* __restrict__ my, float* __restrict__ out)
{
  __shared__ union {
    struct { ushort xs[FNQB][FXP]; ushort ms[FNJB][FMP]; float mnv[FNJB]; } m;
    struct { float Lv[FNQB][8][KSEL]; int Lj[FNQB][8][KSEL]; } e;
  } sm;
  const int t = threadIdx.x, w = t >> 6, l = t & 63;
  const int wj = w >> 1, wq = w & 1, lr = l & 15, lg = l >> 4;
  const int qflat = blockIdx.x * FNQB, bb = qflat >> 14, hw0 = qflat & (HW - 1);
  const float* xbase = x + (size_t)bb * C_DIM * HW + hw0;
  {
    const int q = t & 63, cpb = t >> 6;
#pragma unroll 8
    for (int k = 0; k < 32; ++k) {
      const int cp = cpb + 4 * k;
      ((uint*)&sm.m.xs[q][0])[cp] =
          pk2(xbase[(size_t)(2 * cp) * HW + q], xbase[(size_t)(2 * cp + 1) * HW + q]);
    }
  }
  float lv[2][KSEL]; int lj[2][KSEL]; float thr[2];
#pragma unroll
  for (int qf = 0; qf < 2; ++qf) {
    thr[qf] = INFV;
#pragma unroll
    for (int e = 0; e < KSEL; ++e) { lv[qf][e] = INFV; lj[qf][e] = 0x7fffffff; }
  }
  const int srow = t >> 1, sh = t & 1;
  for (int jt = 0; jt < FNT; ++jt) {
    const int j0 = jt * FNJB;
    f32x4 acc[4][2];
#pragma unroll
    for (int jf = 0; jf < 4; ++jf)
#pragma unroll
      for (int qf = 0; qf < 2; ++qf) acc[jf][qf] = (f32x4){0.f, 0.f, 0.f, 0.f};
    float np = 0.f;
    for (int ks = 0; ks < 8; ++ks) {
      int jr = j0 + srow; jr = (jr < M_PTS) ? jr : (M_PTS - 1);
      const float4* src = (const float4*)(mx + (size_t)jr * C_DIM + ks * 32 + sh * 16);
      const float4 v0 = src[0], v1 = src[1], v2 = src[2], v3 = src[3];
      __syncthreads();
      uint* dst = (uint*)&sm.m.ms[srow][sh * 16];
      dst[0] = pk2(v0.x, v0.y); dst[1] = pk2(v0.z, v0.w);
      dst[2] = pk2(v1.x, v1.y); dst[3] = pk2(v1.z, v1.w);
      dst[4] = pk2(v2.x, v2.y); dst[5] = pk2(v2.z, v2.w);
      dst[6] = pk2(v3.x, v3.y); dst[7] = pk2(v3.z, v3.w);
      np = fmaf(v0.x, v0.x, np); np = fmaf(v0.y, v0.y, np);
      np = fmaf(v0.z, v0.z, np); np = fmaf(v0.w, v0.w, np);
      np = fmaf(v1.x, v1.x, np); np = fmaf(v1.y, v1.y, np);
      np = fmaf(v1.z, v1.z, np); np = fmaf(v1.w, v1.w, np);
      np = fmaf(v2.x, v2.x, np); np = fmaf(v2.y, v2.y, np);
      np = fmaf(v2.z, v2.z, np); np = fmaf(v2.w, v2.w, np);
      np = fmaf(v3.x, v3.x, np); np = fmaf(v3.y, v3.y, np);
      np = fmaf(v3.z, v3.z, np); np = fmaf(v3.w, v3.w, np);
      if (ks == 7) {
        const float full = np + __shfl_xor(np, 1);
        if (sh == 0) sm.m.mnv[srow] = full;
      }
      __syncthreads();
      const short8 bq0 = *(const short8*)&sm.m.xs[wq * 32 + lr][ks * 32 + 8 * lg];
      const short8 bq1 = *(const short8*)&sm.m.xs[wq * 32 + 16 + lr][ks * 32 + 8 * lg];
#pragma unroll
      for (int jf = 0; jf < 4; ++jf) {
        const short8 af = *(const short8*)&sm.m.ms[wj * 64 + jf * 16 + lr][8 * lg];
        acc[jf][0] = MFMA16(af, bq0, acc[jf][0]);
        acc[jf][1] = MFMA16(af, bq1, acc[jf][1]);
      }
    }
#pragma unroll
    for (int jf = 0; jf < 4; ++jf) {
      const f32x4 mn4 = *(const f32x4*)&sm.m.mnv[wj * 64 + jf * 16 + 4 * lg];
      const int jb = j0 + wj * 64 + jf * 16 + 4 * lg;
#pragma unroll
      for (int qf = 0; qf < 2; ++qf) {
#pragma unroll
        for (int e = 0; e < 4; ++e) {
          const int jg = jb + e;
          const float sc = fmaf(-2.f, acc[jf][qf][e], mn4[e]);
          if (jg < M_PTS && sc < thr[qf]) {
            const float v0 = lv[qf][0], v1 = lv[qf][1], v2 = lv[qf][2], v3 = lv[qf][3];
            const int   i0 = lj[qf][0], i1 = lj[qf][1], i2 = lj[qf][2], i3 = lj[qf][3];
            const bool c0 = sc < v0, c1 = sc < v1, c2 = sc < v2, c3 = sc < v3;
            lv[qf][4] = c3 ? v3 : sc;             lj[qf][4] = c3 ? i3 : jg;
            lv[qf][3] = c3 ? (c2 ? v2 : sc) : v3; lj[qf][3] = c3 ? (c2 ? i2 : jg) : i3;
            lv[qf][2] = c2 ? (c1 ? v1 : sc) : v2; lj[qf][2] = c2 ? (c1 ? i1 : jg) : i2;
            lv[qf][1] = c1 ? (c0 ? v0 : sc) : v1; lj[qf][1] = c1 ? (c0 ? i0 : jg) : i1;
            lv[qf][0] = c0 ? sc : v0;             lj[qf][0] = c0 ? jg : i0;
            thr[qf] = lv[qf][4];
          }
        }
      }
    }
  }
  __syncthreads();
#pragma unroll
  for (int qf = 0; qf < 2; ++qf) {
    const int q = wq * 32 + qf * 16 + lr, s = wj * 4 + lg;
#pragma unroll
    for (int e = 0; e < KSEL; ++e) { sm.e.Lv[q][s][e] = lv[qf][e]; sm.e.Lj[q][s][e] = lj[qf][e]; }
  }
  __syncthreads();
  if (t < FNQB) {
    float bv[8]; int bj2[8];
#pragma unroll
    for (int k = 0; k < 8; ++k) { bv[k] = INFV; bj2[k] = 0x7fffffff; }
    for (int s = 0; s < 8; ++s) {
#pragma unroll
      for (int e = 0; e < KSEL; ++e) {
        const float v = sm.e.Lv[t][s][e]; const int j = sm.e.Lj[t][s][e];
        if (v < bv[7] || (v == bv[7] && j < bj2[7])) {
          int pos = 7;
          while (pos > 0 && (bv[pos - 1] > v || (bv[pos - 1] == v && bj2[pos - 1] > j))) {
            bv[pos] = bv[pos - 1]; bj2[pos] = bj2[pos - 1]; --pos;
          }
          bv[pos] = v; bj2[pos] = j;
        }
      }
    }
    const float *m0 = mx + (size_t)bj2[0] * C_DIM, *m1 = mx + (size_t)bj2[1] * C_DIM;
    const float *m2 = mx + (size_t)bj2[2] * C_DIM, *m3 = mx + (size_t)bj2[3] * C_DIM;
    const float *m4 = mx + (size_t)bj2[4] * C_DIM, *m5 = mx + (size_t)bj2[5] * C_DIM;
    const float *m6 = mx + (size_t)bj2[6] * C_DIM, *m7 = mx + (size_t)bj2[7] * C_DIM;
    const float* xq = xbase + t;
    double d0 = 0, d1 = 0, d2 = 0, d3 = 0, d4 = 0, d5 = 0, d6 = 0, d7 = 0;
#pragma unroll 4
    for (int c = 0; c < C_DIM; ++c) {
      const double xv = (double)xq[(size_t)c * HW];
      double dd;
      dd = xv - (double)m0[c]; d0 = fma(dd, dd, d0);
      dd = xv - (double)m1[c]; d1 = fma(dd, dd, d1);
      dd = xv - (double)m2[c]; d2 = fma(dd, dd, d2);
      dd = xv - (double)m3[c]; d3 = fma(dd, dd, d3);
      dd = xv - (double)m4[c]; d4 = fma(dd, dd, d4);
      dd = xv - (double)m5[c]; d5 = fma(dd, dd, d5);
      dd = xv - (double)m6[c]; d6 = fma(dd, dd, d6);
      dd = xv - (double)m7[c]; d7 = fma(dd, dd, d7);
    }
    const double dv[8] = {d0, d1, d2, d3, d4, d5, d6, d7};
    const int jvv[8] = {bj2[0], bj2[1], bj2[2], bj2[3], bj2[4], bj2[5], bj2[6], bj2[7]};
    int labs[KSEL]; unsigned used = 0;
#pragma unroll
    for (int n = 0; n < KSEL; ++n) {
      double bd = 1e300; int bj = 0x7fffffff; int bk = 0;
#pragma unroll
      for (int k = 0; k < 8; ++k) {
        const bool avail = ((used >> k) & 1u) == 0u;
        if (avail && (dv[k] < bd || (dv[k] == bd && jvv[k] < bj))) {
          bd = dv[k]; bj = jvv[k]; bk = k;
        }
      }
      used |= (1u << bk);
      labs[n] = my[bj];
    }
    int bestLab = NUM_CLASSES, bestCnt = 0;
#pragma unroll
    for (int a = 0; a < KSEL; ++a) {
      int cnt = 0;
#pragma unroll
      for (int b2 = 0; b2 < KSEL; ++b2) cnt += (labs[b2] == labs[a]) ? 1 : 0;
      if (cnt > bestCnt || (cnt == bestCnt && labs[a] < bestLab)) { bestCnt = cnt; bestLab = labs[a]; }
    }
    float* ob = out + (size_t)bb * NUM_CLASSES * HW + hw0 + t;
#pragma unroll
    for (int cls = 0; cls < NUM_CLASSES; ++cls)
      ob[(size_t)cls * HW] = (cls == bestLab) ? 1.0f : 0.0f;
  }
}

extern "C" void kernel_launch(void* const* d_in, const int* in_sizes, int n_in,
                              void* d_out, int out_size, void* d_ws, size_t ws_size,
                              hipStream_t stream) {
  (void)in_sizes; (void)n_in; (void)out_size;
  const float* x  = (const float*)d_in[0];
  const float* mx = (const float*)d_in[2];   // d_in[1] (y) unused by reference
  const int*   my = (const int*)d_in[3];
  float* out = (float*)d_out;
  if (ws_size >= (size_t)WS_TOTAL) {
    float*  mn = (float*)((char*)d_ws + WS_MN_OFF);
    ushort* mw = (ushort*)((char*)d_ws + WS_MW_OFF);
    ushort* xb = (ushort*)((char*)d_ws + WS_XB_OFF);
    conv_m<<<MPAD / 64, 256, 0, stream>>>(mx, mw, mn);
    conv_x<<<32768 / 64, 256, 0, stream>>>(x, xb);
    knn_big<<<32768 / NQB, 512, 0, stream>>>(x, mx, mw, mn, xb, my, out);
  } else {
    knn_fb<<<32768 / FNQB, 256, 0, stream>>>(x, mx, my, out);
  }
}

// Round 16
// 691.278 us; speedup vs baseline: 1.4076x; 1.4076x over previous
//
#include <hip/hip_runtime.h>
#include <cstdint>

#define NUM_CLASSES 20
#define KSEL 5
#define M_PTS 10000
#define C_DIM 256
#define HW 16384
#define NQB 32           // queries per block (4 blocks/CU)
#define NJB 64           // j rows per tile
#define NT 158           // 158*64 = 10112 >= 10000
#define MPAD 10112
#define INFV 1e30f

// ws layout (bytes)
#define WS_MN_OFF 0                      // float mn[10112]          = 40448 B
#define WS_MW_OFF 40448u                 // ushort mw[10000*256]     = 5120000 B
#define WS_XB_OFF 5160448u               // ushort xb[32768*256]     = 16777216 B
#define WS_TOTAL  21937664u

typedef short short8 __attribute__((ext_vector_type(8)));
typedef float f32x4 __attribute__((ext_vector_type(4)));

#define MFMA16(a, b, c) __builtin_amdgcn_mfma_f32_16x16x32_bf16(a, b, c, 0, 0, 0)

__device__ __forceinline__ uint pk2(float a, float b) {   // RNE f32->bf16 pair
  uint ua = __float_as_uint(a), ub = __float_as_uint(b);
  ua = (ua + 0x7fffu + ((ua >> 16) & 1u)) >> 16;
  ub = (ub + 0x7fffu + ((ub >> 16) & 1u)) >> 16;
  return (ua & 0xffffu) | (ub << 16);
}

__device__ __forceinline__ void gl16(const ushort* g, ushort* l) {
  __builtin_amdgcn_global_load_lds(
      (const __attribute__((address_space(1))) uint*)g,
      (__attribute__((address_space(3))) uint*)l, 16, 0, 0);
}

// per-wave waits (no barriers): rule-18 pattern -- asm wait + sched_barrier
#define VMWAIT0()  do { asm volatile("s_waitcnt vmcnt(0)" ::: "memory"); \
                        __builtin_amdgcn_sched_barrier(0); } while (0)
#define LGKM0()    do { asm volatile("s_waitcnt lgkmcnt(0)" ::: "memory"); \
                        __builtin_amdgcn_sched_barrier(0); } while (0)
#define SBAR()     __builtin_amdgcn_sched_barrier(0)

// ---- prep 1: m -> bf16 rows + fp32 norms (INF for padded rows) ----
__global__ void conv_m(const float* __restrict__ mx, ushort* __restrict__ mw,
                       float* __restrict__ mn) {
  const int t = threadIdx.x;
  const int r = blockIdx.x * 64 + (t >> 2);
  const int sg = t & 3;
  if (r >= MPAD) return;
  if (r >= M_PTS) { if (sg == 0) mn[r] = INFV; return; }
  const float4* src = (const float4*)(mx + (size_t)r * C_DIM + sg * 64);
  float4 v[16];
#pragma unroll
  for (int k = 0; k < 16; ++k) v[k] = src[k];
  uint u[32];
  float np = 0.f;
#pragma unroll
  for (int k = 0; k < 16; ++k) {
    u[2 * k]     = pk2(v[k].x, v[k].y);
    u[2 * k + 1] = pk2(v[k].z, v[k].w);
    np = fmaf(v[k].x, v[k].x, np); np = fmaf(v[k].y, v[k].y, np);
    np = fmaf(v[k].z, v[k].z, np); np = fmaf(v[k].w, v[k].w, np);
  }
  uint4* dst = (uint4*)(mw + (size_t)r * C_DIM + sg * 64);
#pragma unroll
  for (int i = 0; i < 8; ++i) dst[i] = *(const uint4*)&u[4 * i];
  np += __shfl_xor(np, 1);
  np += __shfl_xor(np, 2);
  if (sg == 0) mn[r] = np;
}

// ---- prep 2: x[b][c][hw] -> xb[n][c] bf16 (n = b*16384 + hw) ----
__global__ void conv_x(const float* __restrict__ x, ushort* __restrict__ xb) {
  const int t = threadIdx.x;
  const int n = blockIdx.x * 64 + (t & 63);
  const int seg = t >> 6;                      // c range [seg*64, seg*64+64)
  const int bb = n >> 14, hw = n & (HW - 1);
  const float* src = x + (size_t)bb * C_DIM * HW + hw;
  uint u[32];
#pragma unroll 8
  for (int k = 0; k < 32; ++k) {
    const int c = seg * 64 + 2 * k;
    const float a0 = src[(size_t)c * HW];      // coalesced across lanes
    const float a1 = src[(size_t)(c + 1) * HW];
    u[k] = pk2(a0, a1);
  }
  uint4* dst = (uint4*)(xb + (size_t)n * C_DIM + seg * 64);
#pragma unroll
  for (int i = 0; i < 8; ++i) dst[i] = *(const uint4*)&u[4 * i];
}

// ---- main: 1024 blocks x 256 thr -> 4 blocks/CU (16 waves/CU, 4/SIMD).
// NO __syncthreads in the main loop: wave w stages its OWN 16 rows x 64-tile
// into its private 8 KB LDS slice (gl_lds, XOR-swizzled src, linear dest) and
// is the only consumer. Per-wave sync only: vmcnt(0) before ds_reads,
// lgkmcnt(0) before re-staging (WAR). All 16 waves/CU free-run -> m114-style
// phase diversity hides every drain. bq (x frags, 32 q) = 64 VGPR.
__global__ __launch_bounds__(256, 4) void knn_big(
    const float* __restrict__ x, const float* __restrict__ mx,
    const ushort* __restrict__ mw, const float* __restrict__ mn,
    const ushort* __restrict__ xb, const int* __restrict__ my,
    float* __restrict__ out)
{
  __shared__ union {
    ushort As[4][16][C_DIM];                                      // 32 KB
    struct { float Lv[16][KSEL][NQB]; int Lj[16][KSEL][NQB]; } e; // 20 KB overlay
  } sm;

  const int t  = threadIdx.x;
  const int w  = t >> 6;        // wave: owns tile-rows w*16 .. +16
  const int l  = t & 63;
  const int lr = l & 15;
  const int lg = l >> 4;

  const int q0  = blockIdx.x * NQB;
  const int bb  = q0 >> 14;
  const int hw0 = q0 & (HW - 1);

  // ---- B fragments in registers: 2 qf x 8 ks (64 VGPR), loaded once ----
  short8 bq[2][8];
#pragma unroll
  for (int qf = 0; qf < 2; ++qf) {
    const ushort* xrow = xb + (size_t)(q0 + qf * 16 + lr) * C_DIM;
#pragma unroll
    for (int ks = 0; ks < 8; ++ks)
      bq[qf][ks] = *(const short8*)(xrow + ks * 32 + lg * 8);
  }

  float lv[2][KSEL]; int lj[2][KSEL];
#pragma unroll
  for (int qf = 0; qf < 2; ++qf)
#pragma unroll
    for (int e = 0; e < KSEL; ++e) { lv[qf][e] = INFV; lj[qf][e] = 0x7fffffff; }

  const int s_s    = l & 31;    // staging slot within a row-pair
  const int s_rsub = l >> 5;    // 0/1: which row of the pair
  const int xr     = lr & 7;    // read-side XOR key (row = lr within wave slice)
  const float* mnp = mn + w * 16 + 4 * lg;   // walk +64/tile
  ushort* lds_w = &sm.As[w][0][0];           // wave-private slice

  // STAGE(j0): wave stages rows j0 + w*16 .. +16 (clamped; mn INF-pads tail)
#define STAGE(J0S) do {                                                       \
    _Pragma("unroll")                                                         \
    for (int i_ = 0; i_ < 8; ++i_) {                                          \
      const int row_ = 2 * i_ + s_rsub;                                       \
      int jr_ = (J0S) + w * 16 + row_; if (jr_ >= M_PTS) jr_ = M_PTS - 1;     \
      gl16(mw + (size_t)jr_ * C_DIM + ((s_s ^ (row_ & 7)) * 8),               \
           lds_w + (2 * i_) * C_DIM);                                         \
    }                                                                         \
  } while (0)

  STAGE(0);                     // prologue

  for (int jt = 0; jt < NT; ++jt) {
    const int j0 = jt * NJB;

    VMWAIT0();                  // this wave's staged tile landed
    const f32x4 mn4 = *(const f32x4*)(mnp);    // issued early, used in SEL
    mnp += NJB;

    f32x4 acc[2];
    acc[0] = (f32x4){0.f, 0.f, 0.f, 0.f};
    acc[1] = (f32x4){0.f, 0.f, 0.f, 0.f};

    // batch 1: ks 0..3 (frag regs recycled -> lower pressure)
    short8 fA[4];
#pragma unroll
    for (int ks = 0; ks < 4; ++ks)
      fA[ks] = *(const short8*)(lds_w + lr * C_DIM + ((ks * 4 + lg) ^ xr) * 8);
#pragma unroll
    for (int ks = 0; ks < 4; ++ks) {
      acc[0] = MFMA16(fA[ks], bq[0][ks], acc[0]);
      acc[1] = MFMA16(fA[ks], bq[1][ks], acc[1]);
    }
    // batch 2: ks 4..7
    short8 fB[4];
#pragma unroll
    for (int ks = 0; ks < 4; ++ks)
      fB[ks] = *(const short8*)(lds_w + lr * C_DIM + (((ks + 4) * 4 + lg) ^ xr) * 8);

    LGKM0();                    // all 8 ds_reads done -> buffer reusable (WAR)
    if (jt + 1 < NT) STAGE((jt + 1) * NJB);    // pinned after the wait
    SBAR();

#pragma unroll
    for (int ks = 0; ks < 4; ++ks) {
      acc[0] = MFMA16(fB[ks], bq[0][ks + 4], acc[0]);
      acc[1] = MFMA16(fB[ks], bq[1][ks + 4], acc[1]);
    }

    // selection: score = ||m||^2 - 2*dot. Clamped tail rows carry mn=1e30 ->
    // never inserted. Ascending-j + strict '<' == top_k lower-index tie-break.
    const int jb = j0 + w * 16 + 4 * lg;
#pragma unroll
    for (int qf = 0; qf < 2; ++qf) {
#pragma unroll
      for (int e = 0; e < 4; ++e) {
        const float sc = fmaf(-2.f, acc[qf][e], mn4[e]);
        if (sc < lv[qf][4]) {
          const int jg = jb + e;
          const float v0 = lv[qf][0], v1 = lv[qf][1], v2 = lv[qf][2], v3 = lv[qf][3];
          const int   i0 = lj[qf][0], i1 = lj[qf][1], i2 = lj[qf][2], i3 = lj[qf][3];
          const bool c0 = sc < v0, c1 = sc < v1, c2 = sc < v2, c3 = sc < v3;
          lv[qf][4] = c3 ? v3 : sc;             lj[qf][4] = c3 ? i3 : jg;
          lv[qf][3] = c3 ? (c2 ? v2 : sc) : v3; lj[qf][3] = c3 ? (c2 ? i2 : jg) : i3;
          lv[qf][2] = c2 ? (c1 ? v1 : sc) : v2; lj[qf][2] = c2 ? (c1 ? i1 : jg) : i2;
          lv[qf][1] = c1 ? (c0 ? v0 : sc) : v1; lj[qf][1] = c1 ? (c0 ? i0 : jg) : i1;
          lv[qf][0] = c0 ? sc : v0;             lj[qf][0] = c0 ? jg : i0;
        }
      }
    }
  }
#undef STAGE

  // ---- epilogue: 16 lists/query ([s][e][q], q innermost -> conflict-free),
  // merge -> top-8, fp64 re-rank, vote, one-hot write ----
  __syncthreads();                        // main loop done -> overlay safe
  {
    const int s = w * 4 + lg;             // list slot (lg owns rows 4lg..4lg+3)
#pragma unroll
    for (int qf = 0; qf < 2; ++qf) {
      const int q = qf * 16 + lr;
#pragma unroll
      for (int e = 0; e < KSEL; ++e) { sm.e.Lv[s][e][q] = lv[qf][e]; sm.e.Lj[s][e][q] = lj[qf][e]; }
    }
  }
  __syncthreads();

  if (t < NQB) {                          // thread t finalizes query q0 + t
    float bv[8]; int bj2[8];
#pragma unroll
    for (int k = 0; k < 8; ++k) { bv[k] = INFV; bj2[k] = 0x7fffffff; }
    for (int s = 0; s < 16; ++s) {
#pragma unroll
      for (int e = 0; e < KSEL; ++e) {
        const float v = sm.e.Lv[s][e][t];
        const int  j = sm.e.Lj[s][e][t];
        if (v < bv[7] || (v == bv[7] && j < bj2[7])) {
          int pos = 7;
          while (pos > 0 && (bv[pos - 1] > v || (bv[pos - 1] == v && bj2[pos - 1] > j))) {
            bv[pos] = bv[pos - 1]; bj2[pos] = bj2[pos - 1]; --pos;
          }
          bv[pos] = v; bj2[pos] = j;
        }
      }
    }
    const float *m0 = mx + (size_t)bj2[0] * C_DIM, *m1 = mx + (size_t)bj2[1] * C_DIM;
    const float *m2 = mx + (size_t)bj2[2] * C_DIM, *m3 = mx + (size_t)bj2[3] * C_DIM;
    const float *m4 = mx + (size_t)bj2[4] * C_DIM, *m5 = mx + (size_t)bj2[5] * C_DIM;
    const float *m6 = mx + (size_t)bj2[6] * C_DIM, *m7 = mx + (size_t)bj2[7] * C_DIM;
    const float* xq = x + (size_t)bb * C_DIM * HW + hw0 + t;
    double d0 = 0, d1 = 0, d2 = 0, d3 = 0, d4 = 0, d5 = 0, d6 = 0, d7 = 0;
#pragma unroll 4
    for (int c = 0; c < C_DIM; ++c) {
      const double xv = (double)xq[(size_t)c * HW];
      double dd;
      dd = xv - (double)m0[c]; d0 = fma(dd, dd, d0);
      dd = xv - (double)m1[c]; d1 = fma(dd, dd, d1);
      dd = xv - (double)m2[c]; d2 = fma(dd, dd, d2);
      dd = xv - (double)m3[c]; d3 = fma(dd, dd, d3);
      dd = xv - (double)m4[c]; d4 = fma(dd, dd, d4);
      dd = xv - (double)m5[c]; d5 = fma(dd, dd, d5);
      dd = xv - (double)m6[c]; d6 = fma(dd, dd, d6);
      dd = xv - (double)m7[c]; d7 = fma(dd, dd, d7);
    }
    const double dv[8] = {d0, d1, d2, d3, d4, d5, d6, d7};
    const int    jvv[8] = {bj2[0], bj2[1], bj2[2], bj2[3], bj2[4], bj2[5], bj2[6], bj2[7]};
    int labs[KSEL]; unsigned used = 0;
#pragma unroll
    for (int n = 0; n < KSEL; ++n) {
      double bd = 1e300; int bj = 0x7fffffff; int bk = 0;
#pragma unroll
      for (int k = 0; k < 8; ++k) {
        const bool avail = ((used >> k) & 1u) == 0u;
        if (avail && (dv[k] < bd || (dv[k] == bd && jvv[k] < bj))) {
          bd = dv[k]; bj = jvv[k]; bk = k;
        }
      }
      used |= (1u << bk);
      labs[n] = my[bj];
    }
    int bestLab = NUM_CLASSES, bestCnt = 0;
#pragma unroll
    for (int a = 0; a < KSEL; ++a) {
      int cnt = 0;
#pragma unroll
      for (int b2 = 0; b2 < KSEL; ++b2) cnt += (labs[b2] == labs[a]) ? 1 : 0;
      if (cnt > bestCnt || (cnt == bestCnt && labs[a] < bestLab)) {
        bestCnt = cnt; bestLab = labs[a];
      }
    }
    float* ob = out + (size_t)bb * NUM_CLASSES * HW + hw0 + t;
#pragma unroll
    for (int cls = 0; cls < NUM_CLASSES; ++cls)
      ob[(size_t)cls * HW] = (cls == bestLab) ? 1.0f : 0.0f;
  }
}

// ================= fallback (round-6 kernel, proven): used if ws too small ========
#define FNQB 64
#define FNJB 128
#define FNT 79
#define FXP 264
#define FMP 40
__global__ __launch_bounds__(256, 2) void knn_fb(
    const float* __restrict__ x, const float* __restrict__ mx,
    const int* __restrict__ my, float* __restrict__ out)
{
  __shared__ union {
    struct { ushort xs[FNQB][FXP]; ushort ms[FNJB][FMP]; float mnv[FNJB]; } m;
    struct { float Lv[FNQB][8][KSEL]; int Lj[FNQB][8][KSEL]; } e;
  } sm;
  const int t = threadIdx.x, w = t >> 6, l = t & 63;
  const int wj = w >> 1, wq = w & 1, lr = l & 15, lg = l >> 4;
  const int qflat = blockIdx.x * FNQB, bb = qflat >> 14, hw0 = qflat & (HW - 1);
  const float* xbase = x + (size_t)bb * C_DIM * HW + hw0;
  {
    const int q = t & 63, cpb = t >> 6;
#pragma unroll 8
    for (int k = 0; k < 32; ++k) {
      const int cp = cpb + 4 * k;
      ((uint*)&sm.m.xs[q][0])[cp] =
          pk2(xbase[(size_t)(2 * cp) * HW + q], xbase[(size_t)(2 * cp + 1) * HW + q]);
    }
  }
  float lv[2][KSEL]; int lj[2][KSEL]; float thr[2];
#pragma unroll
  for (int qf = 0; qf < 2; ++qf) {
    thr[qf] = INFV;
#pragma unroll
    for (int e = 0; e < KSEL; ++e) { lv[qf][e] = INFV; lj[qf][e] = 0x7fffffff; }
  }
  const int srow = t >> 1, sh = t & 1;
  for (int jt = 0; jt < FNT; ++jt) {
    const int j0 = jt * FNJB;
    f32x4 acc[4][2];
#pragma unroll
    for (int jf = 0; jf < 4; ++jf)
#pragma unroll
      for (int qf = 0; qf < 2; ++qf) acc[jf][qf] = (f32x4){0.f, 0.f, 0.f, 0.f};
    float np = 0.f;
    for (int ks = 0; ks < 8; ++ks) {
      int jr = j0 + srow; jr = (jr < M_PTS) ? jr : (M_PTS - 1);
      const float4* src = (const float4*)(mx + (size_t)jr * C_DIM + ks * 32 + sh * 16);
      const float4 v0 = src[0], v1 = src[1], v2 = src[2], v3 = src[3];
      __syncthreads();
      uint* dst = (uint*)&sm.m.ms[srow][sh * 16];
      dst[0] = pk2(v0.x, v0.y); dst[1] = pk2(v0.z, v0.w);
      dst[2] = pk2(v1.x, v1.y); dst[3] = pk2(v1.z, v1.w);
      dst[4] = pk2(v2.x, v2.y); dst[5] = pk2(v2.z, v2.w);
      dst[6] = pk2(v3.x, v3.y); dst[7] = pk2(v3.z, v3.w);
      np = fmaf(v0.x, v0.x, np); np = fmaf(v0.y, v0.y, np);
      np = fmaf(v0.z, v0.z, np); np = fmaf(v0.w, v0.w, np);
      np = fmaf(v1.x, v1.x, np); np = fmaf(v1.y, v1.y, np);
      np = fmaf(v1.z, v1.z, np); np = fmaf(v1.w, v1.w, np);
      np = fmaf(v2.x, v2.x, np); np = fmaf(v2.y, v2.y, np);
      np = fmaf(v2.z, v2.z, np); np = fmaf(v2.w, v2.w, np);
      np = fmaf(v3.x, v3.x, np); np = fmaf(v3.y, v3.y, np);
      np = fmaf(v3.z, v3.z, np); np = fmaf(v3.w, v3.w, np);
      if (ks == 7) {
        const float full = np + __shfl_xor(np, 1);
        if (sh == 0) sm.m.mnv[srow] = full;
      }
      __syncthreads();
      const short8 bq0 = *(const short8*)&sm.m.xs[wq * 32 + lr][ks * 32 + 8 * lg];
      const short8 bq1 = *(const short8*)&sm.m.xs[wq * 32 + 16 + lr][ks * 32 + 8 * lg];
#pragma unroll
      for (int jf = 0; jf < 4; ++jf) {
        const short8 af = *(const short8*)&sm.m.ms[wj * 64 + jf * 16 + lr][8 * lg];
        acc[jf][0] = MFMA16(af, bq0, acc[jf][0]);
        acc[jf][1] = MFMA16(af, bq1, acc[jf][1]);
      }
    }
#pragma unroll
    for (int jf = 0; jf < 4; ++jf) {
      const f32x4 mn4 = *(const f32x4*)&sm.m.mnv[wj * 64 + jf * 16 + 4 * lg];
      const int jb = j0 + wj * 64 + jf * 16 + 4 * lg;
#pragma unroll
      for (int qf = 0; qf < 2; ++qf) {
#pragma unroll
        for (int e = 0; e < 4; ++e) {
          const int jg = jb + e;
          const float sc = fmaf(-2.f, acc[jf][qf][e], mn4[e]);
          if (jg < M_PTS && sc < thr[qf]) {
            const float v0 = lv[qf][0], v1 = lv[qf][1], v2 = lv[qf][2], v3 = lv[qf][3];
            const int   i0 = lj[qf][0], i1 = lj[qf][1], i2 = lj[qf][2], i3 = lj[qf][3];
            const bool c0 = sc < v0, c1 = sc < v1, c2 = sc < v2, c3 = sc < v3;
            lv[qf][4] = c3 ? v3 : sc;             lj[qf][4] = c3 ? i3 : jg;
            lv[qf][3] = c3 ? (c2 ? v2 : sc) : v3; lj[qf][3] = c3 ? (c2 ? i2 : jg) : i3;
            lv[qf][2] = c2 ? (c1 ? v1 : sc) : v2; lj[qf][2] = c2 ? (c1 ? i1 : jg) : i2;
            lv[qf][1] = c1 ? (c0 ? v0 : sc) : v1; lj[qf][1] = c1 ? (c0 ? i0 : jg) : i1;
            lv[qf][0] = c0 ? sc : v0;             lj[qf][0] = c0 ? jg : i0;
            thr[qf] = lv[qf][4];
          }
        }
      }
    }
  }
  __syncthreads();
#pragma unroll
  for (int qf = 0; qf < 2; ++qf) {
    const int q = wq * 32 + qf * 16 + lr, s = wj * 4 + lg;
#pragma unroll
    for (int e = 0; e < KSEL; ++e) { sm.e.Lv[q][s][e] = lv[qf][e]; sm.e.Lj[q][s][e] = lj[qf][e]; }
  }
  __syncthreads();
  if (t < FNQB) {
    float bv[8]; int bj2[8];
#pragma unroll
    for (int k = 0; k < 8; ++k) { bv[k] = INFV; bj2[k] = 0x7fffffff; }
    for (int s = 0; s < 8; ++s) {
#pragma unroll
      for (int e = 0; e < KSEL; ++e) {
        const float v = sm.e.Lv[t][s][e]; const int j = sm.e.Lj[t][s][e];
        if (v < bv[7] || (v == bv[7] && j < bj2[7])) {
          int pos = 7;
          while (pos > 0 && (bv[pos - 1] > v || (bv[pos - 1] == v && bj2[pos - 1] > j))) {
            bv[pos] = bv[pos - 1]; bj2[pos] = bj2[pos - 1]; --pos;
          }
          bv[pos] = v; bj2[pos] = j;
        }
      }
    }
    const float *m0 = mx + (size_t)bj2[0] * C_DIM, *m1 = mx + (size_t)bj2[1] * C_DIM;
    const float *m2 = mx + (size_t)bj2[2] * C_DIM, *m3 = mx + (size_t)bj2[3] * C_DIM;
    const float *m4 = mx + (size_t)bj2[4] * C_DIM, *m5 = mx + (size_t)bj2[5] * C_DIM;
    const float *m6 = mx + (size_t)bj2[6] * C_DIM, *m7 = mx + (size_t)bj2[7] * C_DIM;
    const float* xq = xbase + t;
    double d0 = 0, d1 = 0, d2 = 0, d3 = 0, d4 = 0, d5 = 0, d6 = 0, d7 = 0;
#pragma unroll 4
    for (int c = 0; c < C_DIM; ++c) {
      const double xv = (double)xq[(size_t)c * HW];
      double dd;
      dd = xv - (double)m0[c]; d0 = fma(dd, dd, d0);
      dd = xv - (double)m1[c]; d1 = fma(dd, dd, d1);
      dd = xv - (double)m2[c]; d2 = fma(dd, dd, d2);
      dd = xv - (double)m3[c]; d3 = fma(dd, dd, d3);
      dd = xv - (double)m4[c]; d4 = fma(dd, dd, d4);
      dd = xv - (double)m5[c]; d5 = fma(dd, dd, d5);
      dd = xv - (double)m6[c]; d6 = fma(dd, dd, d6);
      dd = xv - (double)m7[c]; d7 = fma(dd, dd, d7);
    }
    const double dv[8] = {d0, d1, d2, d3, d4, d5, d6, d7};
    const int jvv[8] = {bj2[0], bj2[1], bj2[2], bj2[3], bj2[4], bj2[5], bj2[6], bj2[7]};
    int labs[KSEL]; unsigned used = 0;
#pragma unroll
    for (int n = 0; n < KSEL; ++n) {
      double bd = 1e300; int bj = 0x7fffffff; int bk = 0;
#pragma unroll
      for (int k = 0; k < 8; ++k) {
        const bool avail = ((used >> k) & 1u) == 0u;
        if (avail && (dv[k] < bd || (dv[k] == bd && jvv[k] < bj))) {
          bd = dv[k]; bj = jvv[k]; bk = k;
        }
      }
      used |= (1u << bk);
      labs[n] = my[bj];
    }
    int bestLab = NUM_CLASSES, bestCnt = 0;
#pragma unroll
    for (int a = 0; a < KSEL; ++a) {
      int cnt = 0;
#pragma unroll
      for (int b2 = 0; b2 < KSEL; ++b2) cnt += (labs[b2] == labs[a]) ? 1 : 0;
      if (cnt > bestCnt || (cnt == bestCnt && labs[a] < bestLab)) { bestCnt = cnt; bestLab = labs[a]; }
    }
    float* ob = out + (size_t)bb * NUM_CLASSES * HW + hw0 + t;
#pragma unroll
    for (int cls = 0; cls < NUM_CLASSES; ++cls)
      ob[(size_t)cls * HW] = (cls == bestLab) ? 1.0f : 0.0f;
  }
}

extern "C" void kernel_launch(void* const* d_in, const int* in_sizes, int n_in,
                              void* d_out, int out_size, void* d_ws, size_t ws_size,
                              hipStream_t stream) {
  (void)in_sizes; (void)n_in; (void)out_size;
  const float* x  = (const float*)d_in[0];
  const float* mx = (const float*)d_in[2];   // d_in[1] (y) unused by reference
  const int*   my = (const int*)d_in[3];
  float* out = (float*)d_out;
  if (ws_size >= (size_t)WS_TOTAL) {
    float*  mn = (float*)((char*)d_ws + WS_MN_OFF);
    ushort* mw = (ushort*)((char*)d_ws + WS_MW_OFF);
    ushort* xb = (ushort*)((char*)d_ws + WS_XB_OFF);
    conv_m<<<MPAD / 64, 256, 0, stream>>>(mx, mw, mn);
    conv_x<<<32768 / 64, 256, 0, stream>>>(x, xb);
    knn_big<<<32768 / NQB, 256, 0, stream>>>(x, mx, mw, mn, xb, my, out);
  } else {
    knn_fb<<<32768 / FNQB, 256, 0, stream>>>(x, mx, my, out);
  }
}

// Round 17
// 578.778 us; speedup vs baseline: 1.6812x; 1.1944x over previous
//
#include <hip/hip_runtime.h>
#include <cstdint>

#define NUM_CLASSES 20
#define KSEL 5
#define M_PTS 10000
#define C_DIM 256
#define HW 16384
#define NQB 128          // queries per block (grid 256 = 1 block/CU)
#define NJB 128          // j rows per tile
#define NT 79            // ceil(10000/128); 79*128 = 10112
#define MPAD 10112
#define INFV 1e30f

// ws layout (bytes)
#define WS_MN_OFF 0                      // float mn[10112]          = 40448 B
#define WS_MW_OFF 40448u                 // ushort mw[10000*256]     = 5120000 B
#define WS_XB_OFF 5160448u               // ushort xb[32768*256]     = 16777216 B
#define WS_TOTAL  21937664u

typedef short short8 __attribute__((ext_vector_type(8)));
typedef float f32x4 __attribute__((ext_vector_type(4)));

#define MFMA16(a, b, c) __builtin_amdgcn_mfma_f32_16x16x32_bf16(a, b, c, 0, 0, 0)

__device__ __forceinline__ uint pk2(float a, float b) {   // RNE f32->bf16 pair
  uint ua = __float_as_uint(a), ub = __float_as_uint(b);
  ua = (ua + 0x7fffu + ((ua >> 16) & 1u)) >> 16;
  ub = (ub + 0x7fffu + ((ub >> 16) & 1u)) >> 16;
  return (ua & 0xffffu) | (ub << 16);
}

__device__ __forceinline__ void gl16(const ushort* g, ushort* l) {
  __builtin_amdgcn_global_load_lds(
      (const __attribute__((address_space(1))) uint*)g,
      (__attribute__((address_space(3))) uint*)l, 16, 0, 0);
}

// T3/T4 primitives: counted vmcnt (never 0 in steady state) + raw s_barrier.
#define VMCNT10() do { asm volatile("s_waitcnt vmcnt(10)" ::: "memory"); \
                       __builtin_amdgcn_sched_barrier(0); } while (0)
#define RAWBAR()  do { asm volatile("s_barrier" ::: "memory"); \
                       __builtin_amdgcn_sched_barrier(0); } while (0)

// ---- prep 1: m -> bf16 rows + fp32 norms (INF for padded rows) ----
__global__ void conv_m(const float* __restrict__ mx, ushort* __restrict__ mw,
                       float* __restrict__ mn) {
  const int t = threadIdx.x;
  const int r = blockIdx.x * 64 + (t >> 2);
  const int sg = t & 3;
  if (r >= MPAD) return;
  if (r >= M_PTS) { if (sg == 0) mn[r] = INFV; return; }
  const float4* src = (const float4*)(mx + (size_t)r * C_DIM + sg * 64);
  float4 v[16];
#pragma unroll
  for (int k = 0; k < 16; ++k) v[k] = src[k];
  uint u[32];
  float np = 0.f;
#pragma unroll
  for (int k = 0; k < 16; ++k) {
    u[2 * k]     = pk2(v[k].x, v[k].y);
    u[2 * k + 1] = pk2(v[k].z, v[k].w);
    np = fmaf(v[k].x, v[k].x, np); np = fmaf(v[k].y, v[k].y, np);
    np = fmaf(v[k].z, v[k].z, np); np = fmaf(v[k].w, v[k].w, np);
  }
  uint4* dst = (uint4*)(mw + (size_t)r * C_DIM + sg * 64);
#pragma unroll
  for (int i = 0; i < 8; ++i) dst[i] = *(const uint4*)&u[4 * i];
  np += __shfl_xor(np, 1);
  np += __shfl_xor(np, 2);
  if (sg == 0) mn[r] = np;
}

// ---- prep 2: x[b][c][hw] -> xb[n][c] bf16 (n = b*16384 + hw) ----
__global__ void conv_x(const float* __restrict__ x, ushort* __restrict__ xb) {
  const int t = threadIdx.x;
  const int n = blockIdx.x * 64 + (t & 63);
  const int seg = t >> 6;                      // c range [seg*64, seg*64+64)
  const int bb = n >> 14, hw = n & (HW - 1);
  const float* src = x + (size_t)bb * C_DIM * HW + hw;
  uint u[32];
#pragma unroll 8
  for (int k = 0; k < 32; ++k) {
    const int c = seg * 64 + 2 * k;
    const float a0 = src[(size_t)c * HW];      // coalesced across lanes
    const float a1 = src[(size_t)(c + 1) * HW];
    u[k] = pk2(a0, a1);
  }
  uint4* dst = (uint4*)(xb + (size_t)n * C_DIM + seg * 64);
#pragma unroll
  for (int i = 0; i < 8; ++i) dst[i] = *(const uint4*)&u[4 * i];
}

// ---- main: 256 blocks x 512 thr (8 waves: wj 0..3 x wq 0..1), 1 block/CU.
// LDS double-buffer As[2], gl_lds staged 2 TILES DEEP with counted vmcnt --
// no vmcnt(0) drain ever (T3/T4). Per tile t:
//   issue mn(t) loads (regs)
//   s_waitcnt vmcnt(10)   -- own tile-t gl_lds landed (10 = t+1.gl8 + t.mn2)
//   s_barrier             -- ALL waves' tile-t stages landed (each waited own)
//   16 ds_read_b128 + 64 MFMA on buf[t&1]
//   s_barrier             -- all waves done reading buf[t&1]
//   issue 8 gl_lds for tile t+2 into buf[t&1] (WAR-safe after barrier)
//   selection             -- hides issue latency; compiler waits mn itself
__global__ __launch_bounds__(512, 2) void knn_big(
    const float* __restrict__ x, const float* __restrict__ mx,
    const ushort* __restrict__ mw, const float* __restrict__ mn,
    const ushort* __restrict__ xb, const int* __restrict__ my,
    float* __restrict__ out)
{
  __shared__ union {
    ushort As[2][NJB][C_DIM];                                     // 128 KB
    struct { float Lv[64][16][KSEL]; int Lj[64][16][KSEL]; } e;   // 40 KB overlay
  } sm;

  const int t  = threadIdx.x;
  const int w  = t >> 6;
  const int l  = t & 63;
  const int wj = w >> 1;        // row block: wj*32 .. +32
  const int wq = w & 1;         // col block: wq*64 .. +64
  const int lr = l & 15;
  const int lg = l >> 4;

  const int q0  = blockIdx.x * NQB;
  const int bb  = q0 >> 14;
  const int hw0 = q0 & (HW - 1);

  // ---- B fragments in registers: 4 qf x 8 ks, loaded once ----
  short8 bq[4][8];
#pragma unroll
  for (int qf = 0; qf < 4; ++qf) {
    const ushort* xrow = xb + (size_t)(q0 + wq * 64 + qf * 16 + lr) * C_DIM;
#pragma unroll
    for (int ks = 0; ks < 8; ++ks)
      bq[qf][ks] = *(const short8*)(xrow + ks * 32 + lg * 8);
  }

  float lv[4][KSEL]; int lj[4][KSEL];
#pragma unroll
  for (int qf = 0; qf < 4; ++qf)
#pragma unroll
    for (int e = 0; e < KSEL; ++e) { lv[qf][e] = INFV; lj[qf][e] = 0x7fffffff; }

  const int s_s    = l & 31;    // staging slot within a row-pair
  const int s_rsub = l >> 5;    // 0/1: which row of the pair

  const int br0 = wj * 32 + lr;           // A-frag rows (tile-local)
  const int br1 = br0 + 16;
  const int xr  = lr & 7;                 // XOR key (32,16 = 0 mod 8 -> same for both)

#define STAGE(J0S, BUF) do {                                                  \
    _Pragma("unroll")                                                         \
    for (int i_ = 0; i_ < 8; ++i_) {      /* wave w stages rows w*16..+16 */  \
      const int row_ = w * 16 + 2 * i_ + s_rsub;                              \
      int jr_ = (J0S) + row_; if (jr_ >= M_PTS) jr_ = M_PTS - 1;              \
      gl16(mw + (size_t)jr_ * C_DIM + ((s_s ^ (row_ & 7)) * 8),               \
           &sm.As[BUF][w * 16 + 2 * i_][0]);                                  \
    }                                                                         \
  } while (0)

  // prologue: tiles 0 and 1 in flight (16 gl_lds outstanding)
  STAGE(0, 0);
  STAGE(NJB, 1);

  for (int jt = 0; jt < NT; ++jt) {
    const int j0 = jt * NJB;
    const int buf = jt & 1;

    // mn(t): normal loads; compiler inserts its own (counted) wait before use
    const f32x4 mnr0 = *(const f32x4*)(mn + j0 + wj * 32 + 4 * lg);
    const f32x4 mnr1 = *(const f32x4*)(mn + j0 + wj * 32 + 16 + 4 * lg);

    VMCNT10();                  // own tile-t gl_lds retired (in-order vmcnt)
    RAWBAR();                   // all waves' tile-t stages landed

    f32x4 acc[2][4];
#pragma unroll
    for (int jf = 0; jf < 2; ++jf)
#pragma unroll
      for (int qf = 0; qf < 4; ++qf) acc[jf][qf] = (f32x4){0.f, 0.f, 0.f, 0.f};

#pragma unroll
    for (int ks = 0; ks < 8; ++ks) {
      const int k0 = ks * 4 + lg;
      const short8 af0 = *(const short8*)&sm.As[buf][br0][(k0 ^ xr) * 8];
      const short8 af1 = *(const short8*)&sm.As[buf][br1][(k0 ^ xr) * 8];
#pragma unroll
      for (int qf = 0; qf < 4; ++qf) {
        acc[0][qf] = MFMA16(af0, bq[qf][ks], acc[0][qf]);
        acc[1][qf] = MFMA16(af1, bq[qf][ks], acc[1][qf]);
      }
    }

    RAWBAR();                   // all waves done reading buf -> WAR-safe
    if (jt + 2 < NT) STAGE((jt + 2) * NJB, buf);   // refill 2 ahead

    // selection: score = ||m||^2 - 2*dot. Clamped/padded rows carry mn=1e30 ->
    // never inserted. Ascending-j + strict '<' == top_k lower-index tie-break.
#pragma unroll
    for (int jf = 0; jf < 2; ++jf) {
      const f32x4 mn4 = (jf == 0) ? mnr0 : mnr1;
      const int jb = j0 + wj * 32 + jf * 16 + 4 * lg;
#pragma unroll
      for (int qf = 0; qf < 4; ++qf) {
#pragma unroll
        for (int e = 0; e < 4; ++e) {
          const float sc = fmaf(-2.f, acc[jf][qf][e], mn4[e]);
          if (sc < lv[qf][4]) {
            const int jg = jb + e;
            const float v0 = lv[qf][0], v1 = lv[qf][1], v2 = lv[qf][2], v3 = lv[qf][3];
            const int   i0 = lj[qf][0], i1 = lj[qf][1], i2 = lj[qf][2], i3 = lj[qf][3];
            const bool c0 = sc < v0, c1 = sc < v1, c2 = sc < v2, c3 = sc < v3;
            lv[qf][4] = c3 ? v3 : sc;             lj[qf][4] = c3 ? i3 : jg;
            lv[qf][3] = c3 ? (c2 ? v2 : sc) : v3; lj[qf][3] = c3 ? (c2 ? i2 : jg) : i3;
            lv[qf][2] = c2 ? (c1 ? v1 : sc) : v2; lj[qf][2] = c2 ? (c1 ? i1 : jg) : i2;
            lv[qf][1] = c1 ? (c0 ? v0 : sc) : v1; lj[qf][1] = c1 ? (c0 ? i0 : jg) : i1;
            lv[qf][0] = c0 ? sc : v0;             lj[qf][0] = c0 ? jg : i0;
          }
        }
      }
    }
  }
#undef STAGE

  // ---- epilogue: two passes of 64 queries (40 KB overlay). wq==pass waves own them. ----
#pragma unroll
  for (int pass = 0; pass < 2; ++pass) {
    __syncthreads();                      // full drain + sync -> overlay safe
    if (wq == pass) {
#pragma unroll
      for (int qf = 0; qf < 4; ++qf) {
        const int ql = qf * 16 + lr;      // query - pass*64, in [0,64)
        const int s  = wj * 4 + lg;       // 16 lists per query
#pragma unroll
        for (int e = 0; e < KSEL; ++e) { sm.e.Lv[ql][s][e] = lv[qf][e]; sm.e.Lj[ql][s][e] = lj[qf][e]; }
      }
    }
    __syncthreads();

    if (t < 64) {                         // thread t finalizes query q0 + pass*64 + t
      float bv[8]; int bj2[8];
#pragma unroll
      for (int k = 0; k < 8; ++k) { bv[k] = INFV; bj2[k] = 0x7fffffff; }
      for (int s = 0; s < 16; ++s) {
#pragma unroll
        for (int e = 0; e < KSEL; ++e) {
          const float v = sm.e.Lv[t][s][e];
          const int  j = sm.e.Lj[t][s][e];
          if (v < bv[7] || (v == bv[7] && j < bj2[7])) {
            int pos = 7;
            while (pos > 0 && (bv[pos - 1] > v || (bv[pos - 1] == v && bj2[pos - 1] > j))) {
              bv[pos] = bv[pos - 1]; bj2[pos] = bj2[pos - 1]; --pos;
            }
            bv[pos] = v; bj2[pos] = j;
          }
        }
      }
      const float *m0 = mx + (size_t)bj2[0] * C_DIM, *m1 = mx + (size_t)bj2[1] * C_DIM;
      const float *m2 = mx + (size_t)bj2[2] * C_DIM, *m3 = mx + (size_t)bj2[3] * C_DIM;
      const float *m4 = mx + (size_t)bj2[4] * C_DIM, *m5 = mx + (size_t)bj2[5] * C_DIM;
      const float *m6 = mx + (size_t)bj2[6] * C_DIM, *m7 = mx + (size_t)bj2[7] * C_DIM;
      const float* xq = x + (size_t)bb * C_DIM * HW + hw0 + pass * 64 + t;
      double d0 = 0, d1 = 0, d2 = 0, d3 = 0, d4 = 0, d5 = 0, d6 = 0, d7 = 0;
#pragma unroll 4
      for (int c = 0; c < C_DIM; ++c) {
        const double xv = (double)xq[(size_t)c * HW];
        double dd;
        dd = xv - (double)m0[c]; d0 = fma(dd, dd, d0);
        dd = xv - (double)m1[c]; d1 = fma(dd, dd, d1);
        dd = xv - (double)m2[c]; d2 = fma(dd, dd, d2);
        dd = xv - (double)m3[c]; d3 = fma(dd, dd, d3);
        dd = xv - (double)m4[c]; d4 = fma(dd, dd, d4);
        dd = xv - (double)m5[c]; d5 = fma(dd, dd, d5);
        dd = xv - (double)m6[c]; d6 = fma(dd, dd, d6);
        dd = xv - (double)m7[c]; d7 = fma(dd, dd, d7);
      }
      const double dv[8] = {d0, d1, d2, d3, d4, d5, d6, d7};
      const int    jvv[8] = {bj2[0], bj2[1], bj2[2], bj2[3], bj2[4], bj2[5], bj2[6], bj2[7]};
      int labs[KSEL]; unsigned used = 0;
#pragma unroll
      for (int n = 0; n < KSEL; ++n) {
        double bd = 1e300; int bj = 0x7fffffff; int bk = 0;
#pragma unroll
        for (int k = 0; k < 8; ++k) {
          const bool avail = ((used >> k) & 1u) == 0u;
          if (avail && (dv[k] < bd || (dv[k] == bd && jvv[k] < bj))) {
            bd = dv[k]; bj = jvv[k]; bk = k;
          }
        }
        used |= (1u << bk);
        labs[n] = my[bj];
      }
      int bestLab = NUM_CLASSES, bestCnt = 0;
#pragma unroll
      for (int a = 0; a < KSEL; ++a) {
        int cnt = 0;
#pragma unroll
        for (int b2 = 0; b2 < KSEL; ++b2) cnt += (labs[b2] == labs[a]) ? 1 : 0;
        if (cnt > bestCnt || (cnt == bestCnt && labs[a] < bestLab)) {
          bestCnt = cnt; bestLab = labs[a];
        }
      }
      float* ob = out + (size_t)bb * NUM_CLASSES * HW + hw0 + pass * 64 + t;
#pragma unroll
      for (int cls = 0; cls < NUM_CLASSES; ++cls)
        ob[(size_t)cls * HW] = (cls == bestLab) ? 1.0f : 0.0f;
    }
  }
}

// ================= fallback (round-6 kernel, proven): used if ws too small ========
#define FNQB 64
#define FNJB 128
#define FNT 79
#define FXP 264
#define FMP 40
__global__ __launch_bounds__(256, 2) void knn_fb(
    const float* __restrict__ x, const float* __restrict__ mx,
    const int* __restrict__ my, float* __restrict__ out)
{
  __shared__ union {
    struct { ushort xs[FNQB][FXP]; ushort ms[FNJB][FMP]; float mnv[FNJB]; } m;
    struct { float Lv[FNQB][8][KSEL]; int Lj[FNQB][8][KSEL]; } e;
  } sm;
  const int t = threadIdx.x, w = t >> 6, l = t & 63;
  const int wj = w >> 1, wq = w & 1, lr = l & 15, lg = l >> 4;
  const int qflat = blockIdx.x * FNQB, bb = qflat >> 14, hw0 = qflat & (HW - 1);
  const float* xbase = x + (size_t)bb * C_DIM * HW + hw0;
  {
    const int q = t & 63, cpb = t >> 6;
#pragma unroll 8
    for (int k = 0; k < 32; ++k) {
      const int cp = cpb + 4 * k;
      ((uint*)&sm.m.xs[q][0])[cp] =
          pk2(xbase[(size_t)(2 * cp) * HW + q], xbase[(size_t)(2 * cp + 1) * HW + q]);
    }
  }
  float lv[2][KSEL]; int lj[2][KSEL]; float thr[2];
#pragma unroll
  for (int qf = 0; qf < 2; ++qf) {
    thr[qf] = INFV;
#pragma unroll
    for (int e = 0; e < KSEL; ++e) { lv[qf][e] = INFV; lj[qf][e] = 0x7fffffff; }
  }
  const int srow = t >> 1, sh = t & 1;
  for (int jt = 0; jt < FNT; ++jt) {
    const int j0 = jt * FNJB;
    f32x4 acc[4][2];
#pragma unroll
    for (int jf = 0; jf < 4; ++jf)
#pragma unroll
      for (int qf = 0; qf < 2; ++qf) acc[jf][qf] = (f32x4){0.f, 0.f, 0.f, 0.f};
    float np = 0.f;
    for (int ks = 0; ks < 8; ++ks) {
      int jr = j0 + srow; jr = (jr < M_PTS) ? jr : (M_PTS - 1);
      const float4* src = (const float4*)(mx + (size_t)jr * C_DIM + ks * 32 + sh * 16);
      const float4 v0 = src[0], v1 = src[1], v2 = src[2], v3 = src[3];
      __syncthreads();
      uint* dst = (uint*)&sm.m.ms[srow][sh * 16];
      dst[0] = pk2(v0.x, v0.y); dst[1] = pk2(v0.z, v0.w);
      dst[2] = pk2(v1.x, v1.y); dst[3] = pk2(v1.z, v1.w);
      dst[4] = pk2(v2.x, v2.y); dst[5] = pk2(v2.z, v2.w);
      dst[6] = pk2(v3.x, v3.y); dst[7] = pk2(v3.z, v3.w);
      np = fmaf(v0.x, v0.x, np); np = fmaf(v0.y, v0.y, np);
      np = fmaf(v0.z, v0.z, np); np = fmaf(v0.w, v0.w, np);
      np = fmaf(v1.x, v1.x, np); np = fmaf(v1.y, v1.y, np);
      np = fmaf(v1.z, v1.z, np); np = fmaf(v1.w, v1.w, np);
      np = fmaf(v2.x, v2.x, np); np = fmaf(v2.y, v2.y, np);
      np = fmaf(v2.z, v2.z, np); np = fmaf(v2.w, v2.w, np);
      np = fmaf(v3.x, v3.x, np); np = fmaf(v3.y, v3.y, np);
      np = fmaf(v3.z, v3.z, np); np = fmaf(v3.w, v3.w, np);
      if (ks == 7) {
        const float full = np + __shfl_xor(np, 1);
        if (sh == 0) sm.m.mnv[srow] = full;
      }
      __syncthreads();
      const short8 bq0 = *(const short8*)&sm.m.xs[wq * 32 + lr][ks * 32 + 8 * lg];
      const short8 bq1 = *(const short8*)&sm.m.xs[wq * 32 + 16 + lr][ks * 32 + 8 * lg];
#pragma unroll
      for (int jf = 0; jf < 4; ++jf) {
        const short8 af = *(const short8*)&sm.m.ms[wj * 64 + jf * 16 + lr][8 * lg];
        acc[jf][0] = MFMA16(af, bq0, acc[jf][0]);
        acc[jf][1] = MFMA16(af, bq1, acc[jf][1]);
      }
    }
#pragma unroll
    for (int jf = 0; jf < 4; ++jf) {
      const f32x4 mn4 = *(const f32x4*)&sm.m.mnv[wj * 64 + jf * 16 + 4 * lg];
      const int jb = j0 + wj * 64 + jf * 16 + 4 * lg;
#pragma unroll
      for (int qf = 0; qf < 2; ++qf) {
#pragma unroll
        for (int e = 0; e < 4; ++e) {
          const int jg = jb + e;
          const float sc = fmaf(-2.f, acc[jf][qf][e], mn4[e]);
          if (jg < M_PTS && sc < thr[qf]) {
            const float v0 = lv[qf][0], v1 = lv[qf][1], v2 = lv[qf][2], v3 = lv[qf][3];
            const int   i0 = lj[qf][0], i1 = lj[qf][1], i2 = lj[qf][2], i3 = lj[qf][3];
            const bool c0 = sc < v0, c1 = sc < v1, c2 = sc < v2, c3 = sc < v3;
            lv[qf][4] = c3 ? v3 : sc;             lj[qf][4] = c3 ? i3 : jg;
            lv[qf][3] = c3 ? (c2 ? v2 : sc) : v3; lj[qf][3] = c3 ? (c2 ? i2 : jg) : i3;
            lv[qf][2] = c2 ? (c1 ? v1 : sc) : v2; lj[qf][2] = c2 ? (c1 ? i1 : jg) : i2;
            lv[qf][1] = c1 ? (c0 ? v0 : sc) : v1; lj[qf][1] = c1 ? (c0 ? i0 : jg) : i1;
            lv[qf][0] = c0 ? sc : v0;             lj[qf][0] = c0 ? jg : i0;
            thr[qf] = lv[qf][4];
          }
        }
      }
    }
  }
  __syncthreads();
#pragma unroll
  for (int qf = 0; qf < 2; ++qf) {
    const int q = wq * 32 + qf * 16 + lr, s = wj * 4 + lg;
#pragma unroll
    for (int e = 0; e < KSEL; ++e) { sm.e.Lv[q][s][e] = lv[qf][e]; sm.e.Lj[q][s][e] = lj[qf][e]; }
  }
  __syncthreads();
  if (t < FNQB) {
    float bv[8]; int bj2[8];
#pragma unroll
    for (int k = 0; k < 8; ++k) { bv[k] = INFV; bj2[k] = 0x7fffffff; }
    for (int s = 0; s < 8; ++s) {
#pragma unroll
      for (int e = 0; e < KSEL; ++e) {
        const float v = sm.e.Lv[t][s][e]; const int j = sm.e.Lj[t][s][e];
        if (v < bv[7] || (v == bv[7] && j < bj2[7])) {
          int pos = 7;
          while (pos > 0 && (bv[pos - 1] > v || (bv[pos - 1] == v && bj2[pos - 1] > j))) {
            bv[pos] = bv[pos - 1]; bj2[pos] = bj2[pos - 1]; --pos;
          }
          bv[pos] = v; bj2[pos] = j;
        }
      }
    }
    const float *m0 = mx + (size_t)bj2[0] * C_DIM, *m1 = mx + (size_t)bj2[1] * C_DIM;
    const float *m2 = mx + (size_t)bj2[2] * C_DIM, *m3 = mx + (size_t)bj2[3] * C_DIM;
    const float *m4 = mx + (size_t)bj2[4] * C_DIM, *m5 = mx + (size_t)bj2[5] * C_DIM;
    const float *m6 = mx + (size_t)bj2[6] * C_DIM, *m7 = mx + (size_t)bj2[7] * C_DIM;
    const float* xq = xbase + t;
    double d0 = 0, d1 = 0, d2 = 0, d3 = 0, d4 = 0, d5 = 0, d6 = 0, d7 = 0;
#pragma unroll 4
    for (int c = 0; c < C_DIM; ++c) {
      const double xv = (double)xq[(size_t)c * HW];
      double dd;
      dd = xv - (double)m0[c]; d0 = fma(dd, dd, d0);
      dd = xv - (double)m1[c]; d1 = fma(dd, dd, d1);
      dd = xv - (double)m2[c]; d2 = fma(dd, dd, d2);
      dd = xv - (double)m3[c]; d3 = fma(dd, dd, d3);
      dd = xv - (double)m4[c]; d4 = fma(dd, dd, d4);
      dd = xv - (double)m5[c]; d5 = fma(dd, dd, d5);
      dd = xv - (double)m6[c]; d6 = fma(dd, dd, d6);
      dd = xv - (double)m7[c]; d7 = fma(dd, dd, d7);
    }
    const double dv[8] = {d0, d1, d2, d3, d4, d5, d6, d7};
    const int jvv[8] = {bj2[0], bj2[1], bj2[2], bj2[3], bj2[4], bj2[5], bj2[6], bj2[7]};
    int labs[KSEL]; unsigned used = 0;
#pragma unroll
    for (int n = 0; n < KSEL; ++n) {
      double bd = 1e300; int bj = 0x7fffffff; int bk = 0;
#pragma unroll
      for (int k = 0; k < 8; ++k) {
        const bool avail = ((used >> k) & 1u) == 0u;
        if (avail && (dv[k] < bd || (dv[k] == bd && jvv[k] < bj))) {
          bd = dv[k]; bj = jvv[k]; bk = k;
        }
      }
      used |= (1u << bk);
      labs[n] = my[bj];
    }
    int bestLab = NUM_CLASSES, bestCnt = 0;
#pragma unroll
    for (int a = 0; a < KSEL; ++a) {
      int cnt = 0;
#pragma unroll
      for (int b2 = 0; b2 < KSEL; ++b2) cnt += (labs[b2] == labs[a]) ? 1 : 0;
      if (cnt > bestCnt || (cnt == bestCnt && labs[a] < bestLab)) { bestCnt = cnt; bestLab = labs[a]; }
    }
    float* ob = out + (size_t)bb * NUM_CLASSES * HW + hw0 + t;
#pragma unroll
    for (int cls = 0; cls < NUM_CLASSES; ++cls)
      ob[(size_t)cls * HW] = (cls == bestLab) ? 1.0f : 0.0f;
  }
}

extern "C" void kernel_launch(void* const* d_in, const int* in_sizes, int n_in,
                              void* d_out, int out_size, void* d_ws, size_t ws_size,
                              hipStream_t stream) {
  (void)in_sizes; (void)n_in; (void)out_size;
  const float* x  = (const float*)d_in[0];
  const float* mx = (const float*)d_in[2];   // d_in[1] (y) unused by reference
  const int*   my = (const int*)d_in[3];
  float* out = (float*)d_out;
  if (ws_size >= (size_t)WS_TOTAL) {
    float*  mn = (float*)((char*)d_ws + WS_MN_OFF);
    ushort* mw = (ushort*)((char*)d_ws + WS_MW_OFF);
    ushort* xb = (ushort*)((char*)d_ws + WS_XB_OFF);
    conv_m<<<MPAD / 64, 256, 0, stream>>>(mx, mw, mn);
    conv_x<<<32768 / 64, 256, 0, stream>>>(x, xb);
    knn_big<<<32768 / NQB, 512, 0, stream>>>(x, mx, mw, mn, xb, my, out);
  } else {
    knn_fb<<<32768 / FNQB, 256, 0, stream>>>(x, mx, my, out);
  }
}

// Round 18
// 449.548 us; speedup vs baseline: 2.1645x; 1.2875x over previous
//
#include <hip/hip_runtime.h>
#include <cstdint>

#define NUM_CLASSES 20
#define KSEL 5
#define M_PTS 10000
#define C_DIM 256
#define HW 16384
#define NQB 64           // queries per block (grid 512 -> 2 blocks/CU)
#define NJB 64           // j rows per tile
#define NT 158           // 158*64 = 10112 >= 10000
#define MPAD 10112
#define INFV 1e30f

// ws layout (bytes)
#define WS_MN_OFF 0                      // float mn[10112]          = 40448 B
#define WS_MW_OFF 40448u                 // ushort mw[10000*256]     = 5120000 B
#define WS_XB_OFF 5160448u               // ushort xb[32768*256]     = 16777216 B
#define WS_TOTAL  21937664u

typedef short short8 __attribute__((ext_vector_type(8)));
typedef float f32x4 __attribute__((ext_vector_type(4)));

#define MFMA16(a, b, c) __builtin_amdgcn_mfma_f32_16x16x32_bf16(a, b, c, 0, 0, 0)

__device__ __forceinline__ uint pk2(float a, float b) {   // RNE f32->bf16 pair
  uint ua = __float_as_uint(a), ub = __float_as_uint(b);
  ua = (ua + 0x7fffu + ((ua >> 16) & 1u)) >> 16;
  ub = (ub + 0x7fffu + ((ub >> 16) & 1u)) >> 16;
  return (ua & 0xffffu) | (ub << 16);
}

__device__ __forceinline__ void gl16(const ushort* g, ushort* l) {
  __builtin_amdgcn_global_load_lds(
      (const __attribute__((address_space(1))) uint*)g,
      (__attribute__((address_space(3))) uint*)l, 16, 0, 0);
}

// T3/T4 primitives (R17-verified): counted vmcnt + raw s_barrier, no drains.
#define VMCNT5() do { asm volatile("s_waitcnt vmcnt(5)" ::: "memory"); \
                      __builtin_amdgcn_sched_barrier(0); } while (0)
#define VMCNT1() do { asm volatile("s_waitcnt vmcnt(1)" ::: "memory"); \
                      __builtin_amdgcn_sched_barrier(0); } while (0)
#define RAWBAR() do { asm volatile("s_barrier" ::: "memory"); \
                      __builtin_amdgcn_sched_barrier(0); } while (0)

// ---- prep 1: m -> bf16 rows + fp32 norms (INF for padded rows) ----
__global__ void conv_m(const float* __restrict__ mx, ushort* __restrict__ mw,
                       float* __restrict__ mn) {
  const int t = threadIdx.x;
  const int r = blockIdx.x * 64 + (t >> 2);
  const int sg = t & 3;
  if (r >= MPAD) return;
  if (r >= M_PTS) { if (sg == 0) mn[r] = INFV; return; }
  const float4* src = (const float4*)(mx + (size_t)r * C_DIM + sg * 64);
  float4 v[16];
#pragma unroll
  for (int k = 0; k < 16; ++k) v[k] = src[k];
  uint u[32];
  float np = 0.f;
#pragma unroll
  for (int k = 0; k < 16; ++k) {
    u[2 * k]     = pk2(v[k].x, v[k].y);
    u[2 * k + 1] = pk2(v[k].z, v[k].w);
    np = fmaf(v[k].x, v[k].x, np); np = fmaf(v[k].y, v[k].y, np);
    np = fmaf(v[k].z, v[k].z, np); np = fmaf(v[k].w, v[k].w, np);
  }
  uint4* dst = (uint4*)(mw + (size_t)r * C_DIM + sg * 64);
#pragma unroll
  for (int i = 0; i < 8; ++i) dst[i] = *(const uint4*)&u[4 * i];
  np += __shfl_xor(np, 1);
  np += __shfl_xor(np, 2);
  if (sg == 0) mn[r] = np;
}

// ---- prep 2: x[b][c][hw] -> xb[n][c] bf16 (n = b*16384 + hw) ----
__global__ void conv_x(const float* __restrict__ x, ushort* __restrict__ xb) {
  const int t = threadIdx.x;
  const int n = blockIdx.x * 64 + (t & 63);
  const int seg = t >> 6;                      // c range [seg*64, seg*64+64)
  const int bb = n >> 14, hw = n & (HW - 1);
  const float* src = x + (size_t)bb * C_DIM * HW + hw;
  uint u[32];
#pragma unroll 8
  for (int k = 0; k < 32; ++k) {
    const int c = seg * 64 + 2 * k;
    const float a0 = src[(size_t)c * HW];      // coalesced across lanes
    const float a1 = src[(size_t)(c + 1) * HW];
    u[k] = pk2(a0, a1);
  }
  uint4* dst = (uint4*)(xb + (size_t)n * C_DIM + seg * 64);
#pragma unroll
  for (int i = 0; i < 8; ++i) dst[i] = *(const uint4*)&u[4 * i];
}

// ---- main: 512 blocks x 512 thr -> 2 blocks/CU (16 waves/CU, 4/SIMD).
// R12's occupancy shape x R17's verified counted-vmcnt pipeline.
// Wave (wj 0..3, wq 0..1): rows wj*16..+16, cols wq*32..+32. Per tile:
//   issue mn(t) (1 load)
//   s_waitcnt vmcnt(5)   -- own tile-t stages retired (5 = t+1.gl4 + t.mn1)
//   s_barrier            -- all waves' tile-t stages landed
//   8 ds_read_b128 + 16 MFMA on buf[t&1]
//   s_barrier            -- all reads done -> WAR-safe
//   issue 4 gl_lds for tile t+2 into buf[t&1]
//   selection            -- hides issue latency
// Last tile uses vmcnt(1) (only 5 outstanding -> vmcnt(5) would be a no-op).
__global__ __launch_bounds__(512, 4) void knn_big(
    const float* __restrict__ x, const float* __restrict__ mx,
    const ushort* __restrict__ mw, const float* __restrict__ mn,
    const ushort* __restrict__ xb, const int* __restrict__ my,
    float* __restrict__ out)
{
  __shared__ union {
    ushort As[2][NJB][C_DIM];                                     // 64 KB
    struct { float Lv[16][KSEL][NQB]; int Lj[16][KSEL][NQB]; } e; // 40 KB overlay
  } sm;

  const int t  = threadIdx.x;
  const int w  = t >> 6;
  const int l  = t & 63;
  const int wj = w >> 1;        // row block: wj*16 .. +16
  const int wq = w & 1;         // col block: wq*32 .. +32
  const int lr = l & 15;
  const int lg = l >> 4;

  const int q0  = blockIdx.x * NQB;
  const int bb  = q0 >> 14;
  const int hw0 = q0 & (HW - 1);

  // ---- B fragments in registers: 2 qf x 8 ks, loaded once ----
  short8 bq[2][8];
#pragma unroll
  for (int qf = 0; qf < 2; ++qf) {
    const ushort* xrow = xb + (size_t)(q0 + wq * 32 + qf * 16 + lr) * C_DIM;
#pragma unroll
    for (int ks = 0; ks < 8; ++ks)
      bq[qf][ks] = *(const short8*)(xrow + ks * 32 + lg * 8);
  }

  float lv[2][KSEL]; int lj[2][KSEL];
#pragma unroll
  for (int qf = 0; qf < 2; ++qf)
#pragma unroll
    for (int e = 0; e < KSEL; ++e) { lv[qf][e] = INFV; lj[qf][e] = 0x7fffffff; }

  const int s_s    = l & 31;    // staging slot within a row-pair
  const int s_rsub = l >> 5;    // 0/1: which row of the pair

  const int br0 = wj * 16 + lr;           // A-frag row (tile-local, 0..63)
  const int xr  = lr & 7;                 // XOR key (16 = 0 mod 8)

#define STAGE(J0S, BUF) do {                                                  \
    _Pragma("unroll")                                                         \
    for (int i_ = 0; i_ < 4; ++i_) {      /* wave w stages rows w*8..+8 */    \
      const int row_ = w * 8 + 2 * i_ + s_rsub;                               \
      int jr_ = (J0S) + row_; if (jr_ >= M_PTS) jr_ = M_PTS - 1;              \
      gl16(mw + (size_t)jr_ * C_DIM + ((s_s ^ (row_ & 7)) * 8),               \
           &sm.As[BUF][w * 8 + 2 * i_][0]);                                   \
    }                                                                         \
  } while (0)

  // prologue: tiles 0 and 1 in flight (8 gl_lds outstanding)
  STAGE(0, 0);
  STAGE(NJB, 1);

  for (int jt = 0; jt < NT; ++jt) {
    const int j0 = jt * NJB;
    const int buf = jt & 1;

    // mn(t): 1 f32x4 load; compiler inserts its own counted wait before use
    const f32x4 mn4 = *(const f32x4*)(mn + j0 + wj * 16 + 4 * lg);

    if (jt < NT - 1) { VMCNT5(); }   // own tile-t stages retired (in-order)
    else            { VMCNT1(); }    // final tile: only stage(t).4 + mn.1 left
    RAWBAR();                        // all waves' tile-t stages landed

    f32x4 acc[2];
    acc[0] = (f32x4){0.f, 0.f, 0.f, 0.f};
    acc[1] = (f32x4){0.f, 0.f, 0.f, 0.f};

#pragma unroll
    for (int ks = 0; ks < 8; ++ks) {
      const int k0 = ks * 4 + lg;
      const short8 af0 = *(const short8*)&sm.As[buf][br0][(k0 ^ xr) * 8];
      acc[0] = MFMA16(af0, bq[0][ks], acc[0]);
      acc[1] = MFMA16(af0, bq[1][ks], acc[1]);
    }

    RAWBAR();                        // all waves done reading buf -> WAR-safe
    if (jt + 2 < NT) STAGE((jt + 2) * NJB, buf);   // refill 2 ahead

    // selection: score = ||m||^2 - 2*dot. Clamped/padded rows carry mn=1e30 ->
    // never inserted. Ascending-j + strict '<' == top_k lower-index tie-break.
    const int jb = j0 + wj * 16 + 4 * lg;
#pragma unroll
    for (int qf = 0; qf < 2; ++qf) {
#pragma unroll
      for (int e = 0; e < 4; ++e) {
        const float sc = fmaf(-2.f, acc[qf][e], mn4[e]);
        if (sc < lv[qf][4]) {
          const int jg = jb + e;
          const float v0 = lv[qf][0], v1 = lv[qf][1], v2 = lv[qf][2], v3 = lv[qf][3];
          const int   i0 = lj[qf][0], i1 = lj[qf][1], i2 = lj[qf][2], i3 = lj[qf][3];
          const bool c0 = sc < v0, c1 = sc < v1, c2 = sc < v2, c3 = sc < v3;
          lv[qf][4] = c3 ? v3 : sc;             lj[qf][4] = c3 ? i3 : jg;
          lv[qf][3] = c3 ? (c2 ? v2 : sc) : v3; lj[qf][3] = c3 ? (c2 ? i2 : jg) : i3;
          lv[qf][2] = c2 ? (c1 ? v1 : sc) : v2; lj[qf][2] = c2 ? (c1 ? i1 : jg) : i2;
          lv[qf][1] = c1 ? (c0 ? v0 : sc) : v1; lj[qf][1] = c1 ? (c0 ? i0 : jg) : i1;
          lv[qf][0] = c0 ? sc : v0;             lj[qf][0] = c0 ? jg : i0;
        }
      }
    }
  }
#undef STAGE

  // ---- epilogue (R12-proven): 16 lists/query ([s][e][q], q innermost),
  // merge -> top-8, fp64 re-rank, vote, one-hot write ----
  __syncthreads();                        // full drain + sync -> overlay safe
  {
    const int s = wj * 4 + lg;            // list slot (lg owns rows 4lg..4lg+3)
#pragma unroll
    for (int qf = 0; qf < 2; ++qf) {
      const int q = wq * 32 + qf * 16 + lr;
#pragma unroll
      for (int e = 0; e < KSEL; ++e) { sm.e.Lv[s][e][q] = lv[qf][e]; sm.e.Lj[s][e][q] = lj[qf][e]; }
    }
  }
  __syncthreads();

  if (t < NQB) {                          // thread t finalizes query q0 + t
    float bv[8]; int bj2[8];
#pragma unroll
    for (int k = 0; k < 8; ++k) { bv[k] = INFV; bj2[k] = 0x7fffffff; }
    for (int s = 0; s < 16; ++s) {
#pragma unroll
      for (int e = 0; e < KSEL; ++e) {
        const float v = sm.e.Lv[s][e][t];
        const int  j = sm.e.Lj[s][e][t];
        if (v < bv[7] || (v == bv[7] && j < bj2[7])) {
          int pos = 7;
          while (pos > 0 && (bv[pos - 1] > v || (bv[pos - 1] == v && bj2[pos - 1] > j))) {
            bv[pos] = bv[pos - 1]; bj2[pos] = bj2[pos - 1]; --pos;
          }
          bv[pos] = v; bj2[pos] = j;
        }
      }
    }
    const float *m0 = mx + (size_t)bj2[0] * C_DIM, *m1 = mx + (size_t)bj2[1] * C_DIM;
    const float *m2 = mx + (size_t)bj2[2] * C_DIM, *m3 = mx + (size_t)bj2[3] * C_DIM;
    const float *m4 = mx + (size_t)bj2[4] * C_DIM, *m5 = mx + (size_t)bj2[5] * C_DIM;
    const float *m6 = mx + (size_t)bj2[6] * C_DIM, *m7 = mx + (size_t)bj2[7] * C_DIM;
    const float* xq = x + (size_t)bb * C_DIM * HW + hw0 + t;
    double d0 = 0, d1 = 0, d2 = 0, d3 = 0, d4 = 0, d5 = 0, d6 = 0, d7 = 0;
#pragma unroll 4
    for (int c = 0; c < C_DIM; ++c) {
      const double xv = (double)xq[(size_t)c * HW];
      double dd;
      dd = xv - (double)m0[c]; d0 = fma(dd, dd, d0);
      dd = xv - (double)m1[c]; d1 = fma(dd, dd, d1);
      dd = xv - (double)m2[c]; d2 = fma(dd, dd, d2);
      dd = xv - (double)m3[c]; d3 = fma(dd, dd, d3);
      dd = xv - (double)m4[c]; d4 = fma(dd, dd, d4);
      dd = xv - (double)m5[c]; d5 = fma(dd, dd, d5);
      dd = xv - (double)m6[c]; d6 = fma(dd, dd, d6);
      dd = xv - (double)m7[c]; d7 = fma(dd, dd, d7);
    }
    const double dv[8] = {d0, d1, d2, d3, d4, d5, d6, d7};
    const int    jvv[8] = {bj2[0], bj2[1], bj2[2], bj2[3], bj2[4], bj2[5], bj2[6], bj2[7]};
    int labs[KSEL]; unsigned used = 0;
#pragma unroll
    for (int n = 0; n < KSEL; ++n) {
      double bd = 1e300; int bj = 0x7fffffff; int bk = 0;
#pragma unroll
      for (int k = 0; k < 8; ++k) {
        const bool avail = ((used >> k) & 1u) == 0u;
        if (avail && (dv[k] < bd || (dv[k] == bd && jvv[k] < bj))) {
          bd = dv[k]; bj = jvv[k]; bk = k;
        }
      }
      used |= (1u << bk);
      labs[n] = my[bj];
    }
    int bestLab = NUM_CLASSES, bestCnt = 0;
#pragma unroll
    for (int a = 0; a < KSEL; ++a) {
      int cnt = 0;
#pragma unroll
      for (int b2 = 0; b2 < KSEL; ++b2) cnt += (labs[b2] == labs[a]) ? 1 : 0;
      if (cnt > bestCnt || (cnt == bestCnt && labs[a] < bestLab)) {
        bestCnt = cnt; bestLab = labs[a];
      }
    }
    float* ob = out + (size_t)bb * NUM_CLASSES * HW + hw0 + t;
#pragma unroll
    for (int cls = 0; cls < NUM_CLASSES; ++cls)
      ob[(size_t)cls * HW] = (cls == bestLab) ? 1.0f : 0.0f;   // coalesced per plane
  }
}

// ================= fallback (round-6 kernel, proven): used if ws too small ========
#define FNQB 64
#define FNJB 128
#define FNT 79
#define FXP 264
#define FMP 40
__global__ __launch_bounds__(256, 2) void knn_fb(
    const float* __restrict__ x, const float* __restrict__ mx,
    const int* __restrict__ my, float* __restrict__ out)
{
  __shared__ union {
    struct { ushort xs[FNQB][FXP]; ushort ms[FNJB][FMP]; float mnv[FNJB]; } m;
    struct { float Lv[FNQB][8][KSEL]; int Lj[FNQB][8][KSEL]; } e;
  } sm;
  const int t = threadIdx.x, w = t >> 6, l = t & 63;
  const int wj = w >> 1, wq = w & 1, lr = l & 15, lg = l >> 4;
  const int qflat = blockIdx.x * FNQB, bb = qflat >> 14, hw0 = qflat & (HW - 1);
  const float* xbase = x + (size_t)bb * C_DIM * HW + hw0;
  {
    const int q = t & 63, cpb = t >> 6;
#pragma unroll 8
    for (int k = 0; k < 32; ++k) {
      const int cp = cpb + 4 * k;
      ((uint*)&sm.m.xs[q][0])[cp] =
          pk2(xbase[(size_t)(2 * cp) * HW + q], xbase[(size_t)(2 * cp + 1) * HW + q]);
    }
  }
  float lv[2][KSEL]; int lj[2][KSEL]; float thr[2];
#pragma unroll
  for (int qf = 0; qf < 2; ++qf) {
    thr[qf] = INFV;
#pragma unroll
    for (int e = 0; e < KSEL; ++e) { lv[qf][e] = INFV; lj[qf][e] = 0x7fffffff; }
  }
  const int srow = t >> 1, sh = t & 1;
  for (int jt = 0; jt < FNT; ++jt) {
    const int j0 = jt * FNJB;
    f32x4 acc[4][2];
#pragma unroll
    for (int jf = 0; jf < 4; ++jf)
#pragma unroll
      for (int qf = 0; qf < 2; ++qf) acc[jf][qf] = (f32x4){0.f, 0.f, 0.f, 0.f};
    float np = 0.f;
    for (int ks = 0; ks < 8; ++ks) {
      int jr = j0 + srow; jr = (jr < M_PTS) ? jr : (M_PTS - 1);
      const float4* src = (const float4*)(mx + (size_t)jr * C_DIM + ks * 32 + sh * 16);
      const float4 v0 = src[0], v1 = src[1], v2 = src[2], v3 = src[3];
      __syncthreads();
      uint* dst = (uint*)&sm.m.ms[srow][sh * 16];
      dst[0] = pk2(v0.x, v0.y); dst[1] = pk2(v0.z, v0.w);
      dst[2] = pk2(v1.x, v1.y); dst[3] = pk2(v1.z, v1.w);
      dst[4] = pk2(v2.x, v2.y); dst[5] = pk2(v2.z, v2.w);
      dst[6] = pk2(v3.x, v3.y); dst[7] = pk2(v3.z, v3.w);
      np = fmaf(v0.x, v0.x, np); np = fmaf(v0.y, v0.y, np);
      np = fmaf(v0.z, v0.z, np); np = fmaf(v0.w, v0.w, np);
      np = fmaf(v1.x, v1.x, np); np = fmaf(v1.y, v1.y, np);
      np = fmaf(v1.z, v1.z, np); np = fmaf(v1.w, v1.w, np);
      np = fmaf(v2.x, v2.x, np); np = fmaf(v2.y, v2.y, np);
      np = fmaf(v2.z, v2.z, np); np = fmaf(v2.w, v2.w, np);
      np = fmaf(v3.x, v3.x, np); np = fmaf(v3.y, v3.y, np);
      np = fmaf(v3.z, v3.z, np); np = fmaf(v3.w, v3.w, np);
      if (ks == 7) {
        const float full = np + __shfl_xor(np, 1);
        if (sh == 0) sm.m.mnv[srow] = full;
      }
      __syncthreads();
      const short8 bq0 = *(const short8*)&sm.m.xs[wq * 32 + lr][ks * 32 + 8 * lg];
      const short8 bq1 = *(const short8*)&sm.m.xs[wq * 32 + 16 + lr][ks * 32 + 8 * lg];
#pragma unroll
      for (int jf = 0; jf < 4; ++jf) {
        const short8 af = *(const short8*)&sm.m.ms[wj * 64 + jf * 16 + lr][8 * lg];
        acc[jf][0] = MFMA16(af, bq0, acc[jf][0]);
        acc[jf][1] = MFMA16(af, bq1, acc[jf][1]);
      }
    }
#pragma unroll
    for (int jf = 0; jf < 4; ++jf) {
      const f32x4 mn4 = *(const f32x4*)&sm.m.mnv[wj * 64 + jf * 16 + 4 * lg];
      const int jb = j0 + wj * 64 + jf * 16 + 4 * lg;
#pragma unroll
      for (int qf = 0; qf < 2; ++qf) {
#pragma unroll
        for (int e = 0; e < 4; ++e) {
          const int jg = jb + e;
          const float sc = fmaf(-2.f, acc[jf][qf][e], mn4[e]);
          if (jg < M_PTS && sc < thr[qf]) {
            const float v0 = lv[qf][0], v1 = lv[qf][1], v2 = lv[qf][2], v3 = lv[qf][3];
            const int   i0 = lj[qf][0], i1 = lj[qf][1], i2 = lj[qf][2], i3 = lj[qf][3];
            const bool c0 = sc < v0, c1 = sc < v1, c2 = sc < v2, c3 = sc < v3;
            lv[qf][4] = c3 ? v3 : sc;             lj[qf][4] = c3 ? i3 : jg;
            lv[qf][3] = c3 ? (c2 ? v2 : sc) : v3; lj[qf][3] = c3 ? (c2 ? i2 : jg) : i3;
            lv[qf][2] = c2 ? (c1 ? v1 : sc) : v2; lj[qf][2] = c2 ? (c1 ? i1 : jg) : i2;
            lv[qf][1] = c1 ? (c0 ? v0 : sc) : v1; lj[qf][1] = c1 ? (c0 ? i0 : jg) : i1;
            lv[qf][0] = c0 ? sc : v0;             lj[qf][0] = c0 ? jg : i0;
            thr[qf] = lv[qf][4];
          }
        }
      }
    }
  }
  __syncthreads();
#pragma unroll
  for (int qf = 0; qf < 2; ++qf) {
    const int q = wq * 32 + qf * 16 + lr, s = wj * 4 + lg;
#pragma unroll
    for (int e = 0; e < KSEL; ++e) { sm.e.Lv[q][s][e] = lv[qf][e]; sm.e.Lj[q][s][e] = lj[qf][e]; }
  }
  __syncthreads();
  if (t < FNQB) {
    float bv[8]; int bj2[8];
#pragma unroll
    for (int k = 0; k < 8; ++k) { bv[k] = INFV; bj2[k] = 0x7fffffff; }
    for (int s = 0; s < 8; ++s) {
#pragma unroll
      for (int e = 0; e < KSEL; ++e) {
        const float v = sm.e.Lv[t][s][e]; const int j = sm.e.Lj[t][s][e];
        if (v < bv[7] || (v == bv[7] && j < bj2[7])) {
          int pos = 7;
          while (pos > 0 && (bv[pos - 1] > v || (bv[pos - 1] == v && bj2[pos - 1] > j))) {
            bv[pos] = bv[pos - 1]; bj2[pos] = bj2[pos - 1]; --pos;
          }
          bv[pos] = v; bj2[pos] = j;
        }
      }
    }
    const float *m0 = mx + (size_t)bj2[0] * C_DIM, *m1 = mx + (size_t)bj2[1] * C_DIM;
    const float *m2 = mx + (size_t)bj2[2] * C_DIM, *m3 = mx + (size_t)bj2[3] * C_DIM;
    const float *m4 = mx + (size_t)bj2[4] * C_DIM, *m5 = mx + (size_t)bj2[5] * C_DIM;
    const float *m6 = mx + (size_t)bj2[6] * C_DIM, *m7 = mx + (size_t)bj2[7] * C_DIM;
    const float* xq = xbase + t;
    double d0 = 0, d1 = 0, d2 = 0, d3 = 0, d4 = 0, d5 = 0, d6 = 0, d7 = 0;
#pragma unroll 4
    for (int c = 0; c < C_DIM; ++c) {
      const double xv = (double)xq[(size_t)c * HW];
      double dd;
      dd = xv - (double)m0[c]; d0 = fma(dd, dd, d0);
      dd = xv - (double)m1[c]; d1 = fma(dd, dd, d1);
      dd = xv - (double)m2[c]; d2 = fma(dd, dd, d2);
      dd = xv - (double)m3[c]; d3 = fma(dd, dd, d3);
      dd = xv - (double)m4[c]; d4 = fma(dd, dd, d4);
      dd = xv - (double)m5[c]; d5 = fma(dd, dd, d5);
      dd = xv - (double)m6[c]; d6 = fma(dd, dd, d6);
      dd = xv - (double)m7[c]; d7 = fma(dd, dd, d7);
    }
    const double dv[8] = {d0, d1, d2, d3, d4, d5, d6, d7};
    const int jvv[8] = {bj2[0], bj2[1], bj2[2], bj2[3], bj2[4], bj2[5], bj2[6], bj2[7]};
    int labs[KSEL]; unsigned used = 0;
#pragma unroll
    for (int n = 0; n < KSEL; ++n) {
      double bd = 1e300; int bj = 0x7fffffff; int bk = 0;
#pragma unroll
      for (int k = 0; k < 8; ++k) {
        const bool avail = ((used >> k) & 1u) == 0u;
        if (avail && (dv[k] < bd || (dv[k] == bd && jvv[k] < bj))) {
          bd = dv[k]; bj = jvv[k]; bk = k;
        }
      }
      used |= (1u << bk);
      labs[n] = my[bj];
    }
    int bestLab = NUM_CLASSES, bestCnt = 0;
#pragma unroll
    for (int a = 0; a < KSEL; ++a) {
      int cnt = 0;
#pragma unroll
      for (int b2 = 0; b2 < KSEL; ++b2) cnt += (labs[b2] == labs[a]) ? 1 : 0;
      if (cnt > bestCnt || (cnt == bestCnt && labs[a] < bestLab)) { bestCnt = cnt; bestLab = labs[a]; }
    }
    float* ob = out + (size_t)bb * NUM_CLASSES * HW + hw0 + t;
#pragma unroll
    for (int cls = 0; cls < NUM_CLASSES; ++cls)
      ob[(size_t)cls * HW] = (cls == bestLab) ? 1.0f : 0.0f;
  }
}

extern "C" void kernel_launch(void* const* d_in, const int* in_sizes, int n_in,
                              void* d_out, int out_size, void* d_ws, size_t ws_size,
                              hipStream_t stream) {
  (void)in_sizes; (void)n_in; (void)out_size;
  const float* x  = (const float*)d_in[0];
  const float* mx = (const float*)d_in[2];   // d_in[1] (y) unused by reference
  const int*   my = (const int*)d_in[3];
  float* out = (float*)d_out;
  if (ws_size >= (size_t)WS_TOTAL) {
    float*  mn = (float*)((char*)d_ws + WS_MN_OFF);
    ushort* mw = (ushort*)((char*)d_ws + WS_MW_OFF);
    ushort* xb = (ushort*)((char*)d_ws + WS_XB_OFF);
    conv_m<<<MPAD / 64, 256, 0, stream>>>(mx, mw, mn);
    conv_x<<<32768 / 64, 256, 0, stream>>>(x, xb);
    knn_big<<<32768 / NQB, 512, 0, stream>>>(x, mx, mw, mn, xb, my, out);
  } else {
    knn_fb<<<32768 / FNQB, 256, 0, stream>>>(x, mx, my, out);
  }
}